// Round 19
// baseline (406.361 us; speedup 1.0000x reference)
//
#include <hip/hip_runtime.h>
#include <hip/hip_bf16.h>
#include <math.h>

#define NPER 3
#define SEQL 192
#define PREDL 96
#define CH 8
#define FD 1536      // SEQL*CH
#define NT 10000
#define BS 32
#define PB 96        // NPER*BS
#define TOPM 20
#define DM 512
#define HALFW 287    // SEQ+PRED-1
#define NROWS 30000  // NPER*NT
#define NRP2 10112   // NT padded to 79*128
#define NRB2 79
#define NCB 12       // 1536/128 col blocks
#define PCOLS 24     // part slots per row: 12 col-blocks x 2 col-half waves
#define NWG2 (NRB2*NCB)   // 948 per plane
#define NJ 3840      // TOPM*SEQL
#define K0R 384      // reduced K, plane 0 (g=4)
#define K1R 768      // plane 1 (g=2)
#define K2R 1536     // plane 2 (g=1)
#define KS 16        // K-splits for bx/t small GEMMs
#define NCH 8        // top-k chunks
#define CHSZ (NT/NCH)
#define NWTG 4080    // wtg blocks: 85*48
#define NB_DOT (3*NRB2)  // 237 dot blocks: 3 error-split terms x 79 col strips
#define BUFSZ (2*128*32) // one pipeline buffer: A(8KB)+B(8KB) in shorts
#define RSQRT_DM 0.04419417382415922f

typedef __attribute__((ext_vector_type(8))) short bf16x8;
typedef __attribute__((ext_vector_type(4))) float f32x4;
typedef __attribute__((address_space(3))) short lds_short_t;
typedef __attribute__((address_space(1))) const short glb_short_t;

__device__ inline float bflo(unsigned u){ return __uint_as_float(u << 16); }
__device__ inline float bfhi(unsigned u){ return __uint_as_float(u & 0xFFFF0000u); }
__device__ inline float bf2f(unsigned short u){ return __uint_as_float((unsigned)u << 16); }
__device__ inline unsigned short f2bf(float v){
  __hip_bfloat16 h = __float2bfloat16(v);
  return *reinterpret_cast<unsigned short*>(&h);
}

// ---------------- decompose body (+ optional fused hi/lo split of the RAW row).
template<int L>
__device__ __forceinline__ void dec_body(const float* __restrict__ data,
                                         float* __restrict__ mg,
                                         __hip_bfloat16* __restrict__ m0,
                                         __hip_bfloat16* __restrict__ m1,
                                         __hip_bfloat16* __restrict__ m2,
                                         __hip_bfloat16* __restrict__ trH,
                                         __hip_bfloat16* __restrict__ trL,
                                         int N, int n, float* fpool) {
  float* row = fpool;               // L*CH = 1536
  float* m4  = fpool + L*CH;        // (L/4)*CH = 384
  float* m2s = fpool + L*CH + (L/4)*CH;  // (L/2)*CH = 768
  const float* src = data + (size_t)n*L*CH;
  for (int e = threadIdx.x; e < L*CH/4; e += 256)
    *reinterpret_cast<float4*>(&row[e*4]) = *reinterpret_cast<const float4*>(&src[e*4]);
  __syncthreads();
  for (int i = threadIdx.x; i < (L/4)*CH; i += 256) {
    int j = i >> 3, c = i & 7;
    m4[i] = (row[(4*j)*CH+c] + row[(4*j+1)*CH+c] + row[(4*j+2)*CH+c] + row[(4*j+3)*CH+c]) * 0.25f;
  }
  for (int i = threadIdx.x; i < (L/2)*CH; i += 256) {
    int j = i >> 3, c = i & 7;
    m2s[i] = (row[(2*j)*CH+c] + row[(2*j+1)*CH+c]) * 0.5f;
  }
  __syncthreads();
  if (mg) {
    size_t plane = (size_t)N*L*CH;
    size_t base  = (size_t)n*L*CH;
    for (int e = threadIdx.x; e < L*CH/4; e += 256) {
      int i = e*4;
      int l = i >> 3, c0 = i & 7;
      float v0[4], v1[4], v2[4];
      #pragma unroll
      for (int j=0;j<4;j++) {
        int c = c0 + j;
        v0[j] = m4[(l>>2)*CH+c] - m4[(L/4-1)*CH+c];
        v1[j] = m2s[(l>>1)*CH+c] - m2s[(L/2-1)*CH+c];
        v2[j] = row[i+j] - row[(L-1)*CH+c];
      }
      *reinterpret_cast<float4*>(&mg[base+i])           = make_float4(v0[0],v0[1],v0[2],v0[3]);
      *reinterpret_cast<float4*>(&mg[plane+base+i])     = make_float4(v1[0],v1[1],v1[2],v1[3]);
      *reinterpret_cast<float4*>(&mg[2*plane+base+i])   = make_float4(v2[0],v2[1],v2[2],v2[3]);
    }
  }
  if (m0) {
    unsigned short* p0 = (unsigned short*)m0 + (size_t)n*K0R;
    unsigned short* p1 = (unsigned short*)m1 + (size_t)n*K1R;
    unsigned short* p2 = (unsigned short*)m2 + (size_t)n*K2R;
    for (int e = threadIdx.x; e < K0R/4; e += 256) {
      int i = e*4, c0 = i & 7;
      ushort4 u;
      u.x = f2bf(m4[i]   - m4[(L/4-1)*CH + c0]);
      u.y = f2bf(m4[i+1] - m4[(L/4-1)*CH + c0+1]);
      u.z = f2bf(m4[i+2] - m4[(L/4-1)*CH + c0+2]);
      u.w = f2bf(m4[i+3] - m4[(L/4-1)*CH + c0+3]);
      *reinterpret_cast<ushort4*>(&p0[i]) = u;
    }
    for (int e = threadIdx.x; e < K1R/4; e += 256) {
      int i = e*4, c0 = i & 7;
      ushort4 u;
      u.x = f2bf(m2s[i]   - m2s[(L/2-1)*CH + c0]);
      u.y = f2bf(m2s[i+1] - m2s[(L/2-1)*CH + c0+1]);
      u.z = f2bf(m2s[i+2] - m2s[(L/2-1)*CH + c0+2]);
      u.w = f2bf(m2s[i+3] - m2s[(L/2-1)*CH + c0+3]);
      *reinterpret_cast<ushort4*>(&p1[i]) = u;
    }
    for (int e = threadIdx.x; e < K2R/4; e += 256) {
      int i = e*4, c0 = i & 7;
      ushort4 u;
      u.x = f2bf(row[i]   - row[(L-1)*CH + c0]);
      u.y = f2bf(row[i+1] - row[(L-1)*CH + c0+1]);
      u.z = f2bf(row[i+2] - row[(L-1)*CH + c0+2]);
      u.w = f2bf(row[i+3] - row[(L-1)*CH + c0+3]);
      *reinterpret_cast<ushort4*>(&p2[i]) = u;
    }
  }
  if (trH) {
    unsigned short* h = (unsigned short*)trH + (size_t)n*L*CH;
    unsigned short* l = (unsigned short*)trL + (size_t)n*L*CH;
    for (int e = threadIdx.x; e < L*CH/4; e += 256) {
      int i = e*4;
      ushort4 uh, ul;
      uh.x = f2bf(row[i]);   ul.x = f2bf(row[i]   - bf2f(uh.x));
      uh.y = f2bf(row[i+1]); ul.y = f2bf(row[i+1] - bf2f(uh.y));
      uh.z = f2bf(row[i+2]); ul.z = f2bf(row[i+2] - bf2f(uh.z));
      uh.w = f2bf(row[i+3]); ul.w = f2bf(row[i+3] - bf2f(uh.w));
      *reinterpret_cast<ushort4*>(&h[i]) = uh;
      *reinterpret_cast<ushort4*>(&l[i]) = ul;
    }
  }
}

// ---------------- group-summed transposed W builder + attention consts (bxx==84):
__device__ __forceinline__ void wtg_body(const float* __restrict__ W,
                                         __hip_bfloat16* __restrict__ wt0,
                                         __hip_bfloat16* __restrict__ wt1,
                                         __hip_bfloat16* __restrict__ wt2,
                                         const float* __restrict__ Wq,
                                         const float* __restrict__ bq,
                                         const float* __restrict__ Wk,
                                         const float* __restrict__ bk,
                                         float* __restrict__ cst,
                                         int wb, float* fpool) {
  int bxx = wb / 48, byy = wb % 48;
  if (bxx == 84) {
    if (byy != 0) return;
    int tt = threadIdx.x;
    if (tt < 64) {
      int c = tt >> 3, e = tt & 7;
      float s = 0.f;
      for (int d=0; d<DM; d++) s += Wq[c*DM+d] * Wk[e*DM+d];
      cst[tt] = s;
    } else if (tt < 72) {
      int c = tt - 64; float s=0.f;
      for (int d=0;d<DM;d++) s += Wq[c*DM+d]*bk[d];
      cst[tt] = s;
    } else if (tt < 80) {
      int e = tt - 72; float s=0.f;
      for (int d=0;d<DM;d++) s += Wk[e*DM+d]*bq[d];
      cst[tt] = s;
    } else if (tt == 80) {
      float s=0.f;
      for (int d=0;d<DM;d++) s += bq[d]*bk[d];
      cst[80] = s;
    }
    return;
  }
  int G, kr0, Kred;
  __hip_bfloat16* Wt;
  if (bxx < 12)      { G = 4; kr0 = bxx*32;      Kred = K0R; Wt = wt0; }
  else if (bxx < 36) { G = 2; kr0 = (bxx-12)*32; Kred = K1R; Wt = wt1; }
  else               { G = 1; kr0 = (bxx-36)*32; Kred = K2R; Wt = wt2; }
  int f0 = byy*32;
  int k0 = kr0*G;
  int tid = threadIdx.x, tx = tid & 31, ty = tid >> 5;
  for (int i = ty; i < 32*G; i += 8)
    fpool[i*33 + tx] = W[(size_t)(k0+i)*FD + f0 + tx];
  __syncthreads();
  for (int fl = ty; fl < 32; fl += 8) {
    float s = 0.f;
    for (int i=0;i<G;i++) s += fpool[(((tx>>3)*G+i)*8 + (tx&7))*33 + fl];
    Wt[(size_t)(f0+fl)*Kred + kr0 + tx] = __float2bfloat16(s);
  }
}

// ---------------- fused front: decompose(train) | wtg+consts | decompose(x)
__global__ __launch_bounds__(256) void k_front(const float* __restrict__ x,
                                               const float* __restrict__ train,
                                               float* __restrict__ x_mg,
                                               __hip_bfloat16* __restrict__ m0,
                                               __hip_bfloat16* __restrict__ m1,
                                               __hip_bfloat16* __restrict__ m2,
                                               __hip_bfloat16* __restrict__ trH,
                                               __hip_bfloat16* __restrict__ trL,
                                               const float* __restrict__ W,
                                               __hip_bfloat16* __restrict__ wt0,
                                               __hip_bfloat16* __restrict__ wt1,
                                               __hip_bfloat16* __restrict__ wt2,
                                               const float* __restrict__ Wq,
                                               const float* __restrict__ bq,
                                               const float* __restrict__ Wk,
                                               const float* __restrict__ bk,
                                               float* __restrict__ cst) {
  __shared__ float fpool[128*33];
  int bid = blockIdx.x;
  if (bid < NT) {
    dec_body<SEQL>(train, nullptr, m0, m1, m2, trH, trL, NT, bid, fpool);
  } else if (bid < NT + NWTG) {
    wtg_body(W, wt0, wt1, wt2, Wq, bq, Wk, bk, cst, bid - NT, fpool);
  } else {
    dec_body<SEQL>(x, x_mg, nullptr, nullptr, nullptr, nullptr, nullptr,
                   BS, bid - NT - NWTG, fpool);
  }
}

// ---------------- bx partial: bxp[ks][pb][f] = sum over K-slice of x_mg[pb] @ W (96 x 1536)
__global__ __launch_bounds__(256) void k_bx_part(const float* __restrict__ xmg,
                                                 const float* __restrict__ W,
                                                 float* __restrict__ bxp) {
  __shared__ float xs[PB][17];
  __shared__ float Ws[16][65];
  int f0 = blockIdx.x * 64;
  int ks = blockIdx.y;
  int kbase = ks * (FD/KS);
  int tid = threadIdx.x;
  int fl = tid & 63, gp = tid >> 6;
  float acc[24];
  #pragma unroll
  for (int j=0;j<24;j++) acc[j]=0.f;
  for (int k0 = kbase; k0 < kbase + FD/KS; k0 += 16) {
    for (int e = tid; e < PB*16; e += 256) {
      int r = e >> 4, k = e & 15;
      xs[r][k] = xmg[(size_t)r*FD + k0 + k];
    }
    for (int e = tid; e < 16*64; e += 256) {
      int k = e >> 6, f = e & 63;
      Ws[k][f] = W[(size_t)(k0+k)*FD + f0 + f];
    }
    __syncthreads();
    #pragma unroll
    for (int kk = 0; kk < 16; kk++) {
      float w = Ws[kk][fl];
      #pragma unroll
      for (int j=0;j<24;j++) acc[j] += w * xs[gp + 4*j][kk];
    }
    __syncthreads();
  }
  #pragma unroll
  for (int j=0;j<24;j++) {
    int pb = gp + 4*j;
    bxp[((size_t)ks*PB + pb)*FD + f0 + fl] = acc[j];
  }
}

// ---------------- fused: reduce bx partials + bias -> row; l2-normalize -> u; cpb = <u,b>
__global__ __launch_bounds__(256) void k_bxnorm(const float* __restrict__ bxp,
                                                const float* __restrict__ bsim,
                                                float* __restrict__ u_out,
                                                float* __restrict__ cpb) {
  __shared__ float rowv[FD];
  __shared__ float r1[256], r2[256];
  __shared__ float invs;
  int pb = blockIdx.x, tid = threadIdx.x;
  float s2 = 0.f, sb = 0.f;
  for (int f = tid; f < FD; f += 256) {
    float s = 0.f;
    #pragma unroll
    for (int ks=0; ks<KS; ks++) s += bxp[((size_t)ks*PB + pb)*FD + f];
    s += bsim[f];
    rowv[f] = s;
    s2 += s*s; sb += s*bsim[f];
  }
  r1[tid]=s2; r2[tid]=sb; __syncthreads();
  for (int off=128; off>0; off>>=1) {
    if (tid<off) { r1[tid]+=r1[tid+off]; r2[tid]+=r2[tid+off]; }
    __syncthreads();
  }
  if (tid==0) {
    float iv = 1.f / fmaxf(sqrtf(r1[0]), 1e-12f);
    invs = iv;
    cpb[pb] = r2[0] * iv;
  }
  __syncthreads();
  float iv = invs;
  for (int f = tid; f < FD; f += 256) u_out[(size_t)pb*FD + f] = rowv[f]*iv;
}

// ---------------- t partial: tp[ks][pb][k] = sum over f-slice of W[k][f]*u[pb][f]
__global__ __launch_bounds__(256) void k_t_part(const float* __restrict__ u,
                                                const float* __restrict__ W,
                                                float* __restrict__ tp) {
  __shared__ float us[PB][17];
  __shared__ float Wt[64][17];
  int k0 = blockIdx.x * 64;
  int ks = blockIdx.y;
  int fbase = ks * (FD/KS);
  int tid = threadIdx.x;
  int kl = tid & 63, gp = tid >> 6;
  float acc[24];
  #pragma unroll
  for (int j=0;j<24;j++) acc[j]=0.f;
  for (int fc = fbase; fc < fbase + FD/KS; fc += 16) {
    for (int e = tid; e < PB*16; e += 256) {
      int r = e >> 4, f = e & 15;
      us[r][f] = u[(size_t)r*FD + fc + f];
    }
    for (int e = tid; e < 64*16; e += 256) {
      int k = e >> 4, f = e & 15;
      Wt[k][f] = W[(size_t)(k0+k)*FD + fc + f];
    }
    __syncthreads();
    #pragma unroll
    for (int ff = 0; ff < 16; ff++) {
      float w = Wt[kl][ff];
      #pragma unroll
      for (int j=0;j<24;j++) acc[j] += w * us[gp + 4*j][ff];
    }
    __syncthreads();
  }
  #pragma unroll
  for (int j=0;j<24;j++) {
    int pb = gp + 4*j;
    tp[((size_t)ks*PB + pb)*FD + k0 + kl] = acc[j];
  }
}

// ---------------- fused: reduce t partials -> ts; decompose-adjoint -> tadj (bf16 hi/lo split)
__global__ __launch_bounds__(192) void k_tred_adj(const float* __restrict__ tp,
                                                  __hip_bfloat16* __restrict__ tadjH,
                                                  __hip_bfloat16* __restrict__ tadjL) {
  __shared__ float ts[SEQL*CH];
  __shared__ float Tc[CH];
  int pb = blockIdx.x;
  int p = pb / BS;
  int g = (p==0) ? 4 : (p==1) ? 2 : 1;
  int l = threadIdx.x;
  #pragma unroll
  for (int c=0;c<CH;c++) {
    float s = 0.f;
    #pragma unroll
    for (int ks=0; ks<KS; ks++) s += tp[((size_t)ks*PB + pb)*FD + l*CH + c];
    ts[l*CH+c] = s;
  }
  __syncthreads();
  if (l < CH) {
    float s=0.f;
    for (int j=0;j<SEQL;j++) s += ts[j*CH+l];
    Tc[l] = s;
  }
  __syncthreads();
  int j0 = (l/g)*g;
  bool last = (j0 == SEQL-g);
  float ig = 1.f/(float)g;
  unsigned short* th = (unsigned short*)tadjH;
  unsigned short* tl = (unsigned short*)tadjL;
  #pragma unroll
  for (int c=0;c<CH;c++) {
    float s = 0.f;
    for (int jj=0;jj<g;jj++) s += ts[(j0+jj)*CH+c];
    float v = s*ig - (last ? Tc[c]*ig : 0.f);
    unsigned short hv = f2bf(v);
    th[(size_t)pb*FD + l*CH+c] = hv;
    tl[(size_t)pb*FD + l*CH+c] = f2bf(v - bf2f(hv));
  }
}

// ---------------- pipelined staging helpers (T3+T4: counted vmcnt, barrier w/o drain)
#define PIPE_SYNC_4()  do { asm volatile("s_waitcnt vmcnt(4)" ::: "memory"); \
                            __builtin_amdgcn_s_barrier(); \
                            __builtin_amdgcn_sched_barrier(0); } while(0)
#define PIPE_SYNC_0()  do { asm volatile("s_waitcnt vmcnt(0)" ::: "memory"); \
                            __builtin_amdgcn_s_barrier(); \
                            __builtin_amdgcn_sched_barrier(0); } while(0)

// ---------------- norm GEMM body, 3-buffer counted-vmcnt pipeline (depth 2)
__device__ __forceinline__ void norm_body(const short* __restrict__ A,
                                          const short* __restrict__ B,
                                          int K, int p, int seg,
                                          const float* __restrict__ bsim,
                                          float* __restrict__ part,
                                          short* pool) {
  int q = NWG2 >> 3, r = NWG2 & 7;
  int xcd = seg & 7, pos = seg >> 3;
  int wgid = (xcd < r ? xcd*(q+1) : r*(q+1) + (xcd-r)*q) + pos;
  int rb = wgid / NCB, cb = wgid - rb*NCB;
  int row0 = rb*128, col0 = cb*128;
  int tid = threadIdx.x, lane = tid & 63, wid = tid >> 6;
  int wr = (wid>>1)*64, wc = (wid&1)*64;

  size_t aoff[2], boff[2];
  int ldsb[2];
  #pragma unroll
  for (int i=0;i<2;i++) {
    int lrow = (wid*2+i)*16 + (lane>>2);
    int sl = lane & 3;
    int ss = (sl - lrow - (lrow>>2)) & 3;
    aoff[i] = (size_t)(row0 + lrow)*K + 8*ss;
    boff[i] = (size_t)(col0 + lrow)*K + 8*ss;
    ldsb[i] = (wid*2+i)*16*32;
  }

  f32x4 acc[4][4];
  #pragma unroll
  for (int m=0;m<4;m++)
    #pragma unroll
    for (int n=0;n<4;n++) acc[m][n] = (f32x4){0.f,0.f,0.f,0.f};

  int kslot = lane >> 4;
  int nt = K >> 5;
  #pragma unroll
  for (int i=0;i<2;i++) {
    __builtin_amdgcn_global_load_lds((glb_short_t*)(A + aoff[i]),
                                     (lds_short_t*)&pool[ldsb[i]], 16, 0, 0);
    __builtin_amdgcn_global_load_lds((glb_short_t*)(B + boff[i]),
                                     (lds_short_t*)&pool[128*32 + ldsb[i]], 16, 0, 0);
  }
  #pragma unroll
  for (int i=0;i<2;i++) {
    __builtin_amdgcn_global_load_lds((glb_short_t*)(A + aoff[i] + 32),
                                     (lds_short_t*)&pool[BUFSZ + ldsb[i]], 16, 0, 0);
    __builtin_amdgcn_global_load_lds((glb_short_t*)(B + boff[i] + 32),
                                     (lds_short_t*)&pool[BUFSZ + 128*32 + ldsb[i]], 16, 0, 0);
  }
  PIPE_SYNC_4();
  int cur = 0;
  for (int t = 0; t < nt; ++t) {
    if (t + 2 < nt) {
      int nx = cur + 2; if (nx >= 3) nx -= 3;
      short* nb = pool + nx*BUFSZ;
      int kn = (t+2) << 5;
      #pragma unroll
      for (int i=0;i<2;i++) {
        __builtin_amdgcn_global_load_lds((glb_short_t*)(A + aoff[i] + kn),
                                         (lds_short_t*)&nb[ldsb[i]], 16, 0, 0);
        __builtin_amdgcn_global_load_lds((glb_short_t*)(B + boff[i] + kn),
                                         (lds_short_t*)&nb[128*32 + ldsb[i]], 16, 0, 0);
      }
    }
    const short* lA = pool + cur*BUFSZ;
    const short* lB = lA + 128*32;
    bf16x8 af[4], bfr[4];
    #pragma unroll
    for (int m=0;m<4;m++) {
      int rr = wr + m*16 + (lane&15);
      int s = (kslot + rr + (rr>>2)) & 3;
      af[m] = *(const bf16x8*)&lA[rr*32 + s*8];
    }
    #pragma unroll
    for (int n=0;n<4;n++) {
      int rr = wc + n*16 + (lane&15);
      int s = (kslot + rr + (rr>>2)) & 3;
      bfr[n] = *(const bf16x8*)&lB[rr*32 + s*8];
    }
    #pragma unroll
    for (int m=0;m<4;m++)
      #pragma unroll
      for (int n=0;n<4;n++)
        acc[m][n] = __builtin_amdgcn_mfma_f32_16x16x32_bf16(af[m], bfr[n], acc[m][n], 0, 0, 0);
    if (t + 1 < nt) {
      if (t + 2 < nt) PIPE_SYNC_4(); else PIPE_SYNC_0();
    }
    cur = (cur + 1 == 3) ? 0 : cur + 1;
  }

  float bv[4];
  #pragma unroll
  for (int n=0;n<4;n++) bv[n] = bsim[col0 + wc + n*16 + (lane&15)];
  int pslot = cb*2 + (wid&1);
  #pragma unroll
  for (int m=0;m<4;m++) {
    #pragma unroll
    for (int j=0;j<4;j++) {
      float s = 0.f;
      #pragma unroll
      for (int n=0;n<4;n++) { float v = acc[m][n][j] + bv[n]; s += v*v; }
      s += __shfl_xor(s, 1); s += __shfl_xor(s, 2);
      s += __shfl_xor(s, 4); s += __shfl_xor(s, 8);
      if ((lane & 15) == 0) {
        int rr = row0 + wr + m*16 + (lane>>4)*4 + j;
        part[((size_t)p*NRP2 + rr)*PCOLS + pslot] = s;
      }
    }
  }
}

// ---------------- single-term dot GEMM body, same 3-buffer counted-vmcnt pipeline
__device__ __forceinline__ void dot_body(const short* __restrict__ A,
                                         const short* __restrict__ B,
                                         float* __restrict__ dst,
                                         int cbn, short* pool) {
  int col0 = cbn * 128;
  int tid = threadIdx.x, lane = tid & 63, wid = tid >> 6;
  int wr = (wid>>1)*64, wc = (wid&1)*64;

  size_t aoff[2], boff[2];
  int ldsb[2];
  #pragma unroll
  for (int i=0;i<2;i++) {
    int lrow = (wid*2+i)*16 + (lane>>2);
    int sl = lane & 3;
    int ss = (sl - lrow - (lrow>>2)) & 3;
    aoff[i] = (size_t)lrow*FD + 8*ss;
    boff[i] = (size_t)(col0 + lrow)*FD + 8*ss;
    ldsb[i] = (wid*2+i)*16*32;
  }

  f32x4 acc[4][4];
  #pragma unroll
  for (int m=0;m<4;m++)
    #pragma unroll
    for (int n=0;n<4;n++) acc[m][n] = (f32x4){0.f,0.f,0.f,0.f};

  int kslot = lane >> 4;
  const int nt = FD >> 5;
  #pragma unroll
  for (int i=0;i<2;i++) {
    __builtin_amdgcn_global_load_lds((glb_short_t*)(A + aoff[i]),
                                     (lds_short_t*)&pool[ldsb[i]], 16, 0, 0);
    __builtin_amdgcn_global_load_lds((glb_short_t*)(B + boff[i]),
                                     (lds_short_t*)&pool[128*32 + ldsb[i]], 16, 0, 0);
  }
  #pragma unroll
  for (int i=0;i<2;i++) {
    __builtin_amdgcn_global_load_lds((glb_short_t*)(A + aoff[i] + 32),
                                     (lds_short_t*)&pool[BUFSZ + ldsb[i]], 16, 0, 0);
    __builtin_amdgcn_global_load_lds((glb_short_t*)(B + boff[i] + 32),
                                     (lds_short_t*)&pool[BUFSZ + 128*32 + ldsb[i]], 16, 0, 0);
  }
  PIPE_SYNC_4();
  int cur = 0;
  for (int t = 0; t < nt; ++t) {
    if (t + 2 < nt) {
      int nx = cur + 2; if (nx >= 3) nx -= 3;
      short* nb = pool + nx*BUFSZ;
      int kn = (t+2) << 5;
      #pragma unroll
      for (int i=0;i<2;i++) {
        __builtin_amdgcn_global_load_lds((glb_short_t*)(A + aoff[i] + kn),
                                         (lds_short_t*)&nb[ldsb[i]], 16, 0, 0);
        __builtin_amdgcn_global_load_lds((glb_short_t*)(B + boff[i] + kn),
                                         (lds_short_t*)&nb[128*32 + ldsb[i]], 16, 0, 0);
      }
    }
    const short* lA = pool + cur*BUFSZ;
    const short* lB = lA + 128*32;
    bf16x8 af[4], bfr[4];
    #pragma unroll
    for (int m=0;m<4;m++) {
      int rr = wr + m*16 + (lane&15);
      int s = (kslot + rr + (rr>>2)) & 3;
      af[m] = *(const bf16x8*)&lA[rr*32 + s*8];
    }
    #pragma unroll
    for (int n=0;n<4;n++) {
      int rr = wc + n*16 + (lane&15);
      int s = (kslot + rr + (rr>>2)) & 3;
      bfr[n] = *(const bf16x8*)&lB[rr*32 + s*8];
    }
    #pragma unroll
    for (int m=0;m<4;m++)
      #pragma unroll
      for (int n=0;n<4;n++)
        acc[m][n] = __builtin_amdgcn_mfma_f32_16x16x32_bf16(af[m], bfr[n], acc[m][n], 0, 0, 0);
    if (t + 1 < nt) {
      if (t + 2 < nt) PIPE_SYNC_4(); else PIPE_SYNC_0();
    }
    cur = (cur + 1 == 3) ? 0 : cur + 1;
  }

  #pragma unroll
  for (int m=0;m<4;m++) {
    int prow = wr + m*16 + (lane>>4)*4;
    if (prow >= PB) continue;
    #pragma unroll
    for (int n=0;n<4;n++) {
      int ncol = col0 + wc + n*16 + (lane&15);
      if (ncol >= NT) continue;
      #pragma unroll
      for (int j=0;j<4;j++) {
        dst[(size_t)(prow + j)*NT + ncol] = acc[m][n][j];
      }
    }
  }
}

// ---------------- fused GEMMs, uniform 48 KB 3-buf pool. LPT: dot terms | p2 | p1 | p0
__global__ __launch_bounds__(256) void k_gemms(
    const __hip_bfloat16* __restrict__ A0b, const __hip_bfloat16* __restrict__ A1b,
    const __hip_bfloat16* __restrict__ A2b,
    const __hip_bfloat16* __restrict__ B0b, const __hip_bfloat16* __restrict__ B1b,
    const __hip_bfloat16* __restrict__ B2b,
    const float* __restrict__ bsim, float* __restrict__ part,
    const __hip_bfloat16* __restrict__ tadjHb, const __hip_bfloat16* __restrict__ tadjLb,
    const __hip_bfloat16* __restrict__ trHb, const __hip_bfloat16* __restrict__ trLb,
    float* __restrict__ dotp3) {
  __shared__ __align__(16) short pool[3*BUFSZ];
  int bid = blockIdx.x;
  if (bid < NB_DOT) {
    int term = bid / NRB2, cbn = bid - term*NRB2;
    const short* A = (term == 2) ? (const short*)tadjLb : (const short*)tadjHb;
    const short* B = (term == 1) ? (const short*)trLb   : (const short*)trHb;
    dot_body(A, B, dotp3 + (size_t)term*PB*NT, cbn, pool);
  } else if (bid < NB_DOT + NWG2) {
    norm_body((const short*)A2b, (const short*)B2b, K2R, 2, bid - NB_DOT, bsim, part, pool);
  } else if (bid < NB_DOT + 2*NWG2) {
    norm_body((const short*)A1b, (const short*)B1b, K1R, 1, bid - NB_DOT - NWG2, bsim, part, pool);
  } else {
    norm_body((const short*)A0b, (const short*)B0b, K0R, 0,
              bid - NB_DOT - 2*NWG2, bsim, part, pool);
  }
}

// ---------------- top-20 phase A: per-(pb, chunk) local top-20; norm2 computed inline from part
__global__ __launch_bounds__(256) void k_topk_part(const float* __restrict__ dotp3,
                                                   const float* __restrict__ cpb,
                                                   const float* __restrict__ part,
                                                   const int* __restrict__ index,
                                                   float* __restrict__ cv,
                                                   int* __restrict__ ci) {
  __shared__ float vals[CHSZ];
  __shared__ float rv[4];
  __shared__ int   ri[4];
  int pb = blockIdx.x, ch = blockIdx.y;
  int p = pb / BS, b = pb - p*BS;
  int n0 = ch*CHSZ;
  int tid = threadIdx.x, lane = tid & 63, wv = tid >> 6;
  int idx = index[b];
  int bl = idx - HALFW; if (bl < 0) bl = 0;
  int bh = idx + HALFW; if (bh > NT-1) bh = NT-1;
  float cp = cpb[pb];
  for (int i = tid; i < CHSZ; i += 256) {
    int n = n0 + i;
    const float* pr = &part[((size_t)p*NRP2 + n)*PCOLS];
    float s2 = 0.f;
    #pragma unroll
    for (int cb2=0; cb2<PCOLS; cb2++) s2 += pr[cb2];
    float d = dotp3[(size_t)pb*NT + n]
            + dotp3[(size_t)PB*NT + (size_t)pb*NT + n]
            + dotp3[2*(size_t)PB*NT + (size_t)pb*NT + n] + cp;
    float v = d / fmaxf(sqrtf(s2), 1e-12f);
    if (n >= bl && n <= bh) v = -INFINITY;
    vals[i] = v;
  }
  __syncthreads();
  for (int it = 0; it < TOPM; it++) {
    float bv = -INFINITY; int bi = CHSZ;
    for (int i = tid; i < CHSZ; i += 256) {
      float v = vals[i];
      if (v > bv) { bv = v; bi = i; }
    }
    #pragma unroll
    for (int off=32; off>0; off>>=1) {
      float ov = __shfl_xor(bv, off);
      int   oi = __shfl_xor(bi, off);
      if (ov > bv || (ov == bv && oi < bi)) { bv = ov; bi = oi; }
    }
    if (lane == 0) { rv[wv] = bv; ri[wv] = bi; }
    __syncthreads();
    if (tid == 0) {
      float fv = rv[0]; int fi = ri[0];
      #pragma unroll
      for (int w2=1; w2<4; w2++)
        if (rv[w2] > fv || (rv[w2] == fv && ri[w2] < fi)) { fv = rv[w2]; fi = ri[w2]; }
      cv[(pb*NCH + ch)*TOPM + it] = fv;
      ci[(pb*NCH + ch)*TOPM + it] = n0 + fi;
      vals[fi] = -INFINITY;
    }
    __syncthreads();
  }
}

// ---------------- top-20 phase B: merge NCH x 20 candidates (exact; tie -> lower global index)
__global__ __launch_bounds__(64) void k_topk_merge(const float* __restrict__ cv,
                                                   const int* __restrict__ ci,
                                                   int* __restrict__ topm) {
  __shared__ float v[NCH*TOPM];
  __shared__ int   id[NCH*TOPM];
  int pb = blockIdx.x;
  int lane = threadIdx.x;
  for (int i = lane; i < NCH*TOPM; i += 64) {
    v[i]  = cv[pb*NCH*TOPM + i];
    id[i] = ci[pb*NCH*TOPM + i];
  }
  __syncthreads();
  for (int it = 0; it < TOPM; it++) {
    float bv = -INFINITY; int bi = 0x7fffffff;
    for (int i = lane; i < NCH*TOPM; i += 64) {
      float vv = v[i];
      int ii = id[i];
      if (vv > bv || (vv == bv && ii < bi)) { bv = vv; bi = ii; }
    }
    #pragma unroll
    for (int off=32; off>0; off>>=1) {
      float ov = __shfl_xor(bv, off);
      int   oi = __shfl_xor(bi, off);
      if (ov > bv || (ov == bv && oi < bi)) { bv = ov; bi = oi; }
    }
    if (lane == 0) topm[pb*TOPM + it] = bi;
    for (int i = lane; i < NCH*TOPM; i += 64)
      if (id[i] == bi) v[i] = -INFINITY;
    __syncthreads();
  }
}

// ---------------- v body: gathered y_mg rows
__device__ __forceinline__ void v_body(const float* __restrict__ ydata,
                                       const int* __restrict__ topm,
                                       float* __restrict__ vbuf,
                                       int bm, float* bpool) {
  float* row = bpool;          // 768
  float* m4  = bpool + 768;    // 192
  float* m2  = bpool + 960;    // 384
  int pb = bm / TOPM;
  int p = pb / BS;
  int n = topm[bm];
  int tid = threadIdx.x;
  const float* src = ydata + (size_t)n*PREDL*CH;
  for (int i=tid; i<PREDL*CH; i+=256) row[i]=src[i];
  __syncthreads();
  for (int i=tid; i<(PREDL/4)*CH; i+=256) {
    int j=i>>3, c=i&7;
    m4[i] = (row[(4*j)*CH+c]+row[(4*j+1)*CH+c]+row[(4*j+2)*CH+c]+row[(4*j+3)*CH+c])*0.25f;
  }
  for (int i=tid; i<(PREDL/2)*CH; i+=256) {
    int j=i>>3, c=i&7;
    m2[i] = (row[(2*j)*CH+c]+row[(2*j+1)*CH+c])*0.5f;
  }
  __syncthreads();
  float* dst = vbuf + (size_t)bm*PREDL*CH;
  for (int i=tid; i<PREDL*CH; i+=256) {
    int l=i>>3, c=i&7;
    float v;
    if (p==0)      v = m4[(l>>2)*CH+c] - m4[(PREDL/4-1)*CH+c];
    else if (p==1) v = m2[(l>>1)*CH+c] - m2[(PREDL/2-1)*CH+c];
    else           v = row[i] - row[(PREDL-1)*CH+c];
    dst[i] = v;
  }
}

// ---------------- scores body, group-collapsed per plane.
// SH==0 (plane-2) streams K-data from global via hoisted INT OFFSETS (15 VGPRs)
// instead of hoisted uint4 data (60 VGPRs) -> lower kernel-wide register pressure.
// Same addresses, same values, same FMA order -> bit-identical nws.
template<int SH>
__device__ __forceinline__ void scores_body(
    const short* __restrict__ plane, int Kp,
    int pb, int sg,
    const int* __restrict__ topm,
    const float* __restrict__ xmg,
    const float* __restrict__ cst,
    float* __restrict__ nws,
    float* sc, int* tl, float* wred, float* lcst) {
  constexpr int UNQ = SEQL >> SH;      // 48 / 96 / 192
  constexpr int J   = TOPM * UNQ;      // 960 / 1920 / 3840
  constexpr int NU  = (J + 255) >> 8;  // 4 / 8 / 15
  constexpr bool FULL = (J % 256 == 0);
  int tid = threadIdx.x;
  int lane = tid & 63, wv = tid >> 6;
  if (tid < TOPM) tl[tid] = topm[pb*TOPM + tid];
  if (tid >= 32 && tid < 32+81) lcst[tid-32] = cst[tid-32];
  __syncthreads();
  int eoff[NU];
  uint4 kreg[NU];
  #pragma unroll
  for (int u=0; u<NU; u++) {
    int j = tid + u*256;
    if (FULL || j < J) {
      int m = j / UNQ, jj = j - m*UNQ;
      int off = tl[m]*Kp + jj*8;
      if constexpr (SH == 0) eoff[u] = off;
      else kreg[u] = *reinterpret_cast<const uint4*>(plane + off);
    } else {
      if constexpr (SH == 0) eoff[u] = 0;
    }
  }
  for (int s8 = 0; s8 < 8; s8++) {
    int s = sg*8 + s8;
    int qr = pb*SEQL + s;
    float4 qa = *reinterpret_cast<const float4*>(&xmg[(size_t)qr*8]);
    float4 qc = *reinterpret_cast<const float4*>(&xmg[(size_t)qr*8+4]);
    float xq[8] = {qa.x,qa.y,qa.z,qa.w,qc.x,qc.y,qc.z,qc.w};
    float q[8];
    #pragma unroll
    for (int e=0;e<8;e++) {
      float ss = lcst[72+e];
      #pragma unroll
      for (int c=0;c<8;c++) ss += xq[c]*lcst[c*8+e];
      q[e] = ss;
    }
    float qb_s = lcst[80];
    #pragma unroll
    for (int c=0;c<8;c++) qb_s += xq[c]*lcst[64+c];
    float ms[NU];
    float lmax = -INFINITY;
    #pragma unroll
    for (int u=0; u<NU; u++) {
      int j = tid + u*256;
      if (FULL || j < J) {
        uint4 w;
        if constexpr (SH == 0) w = *reinterpret_cast<const uint4*>(plane + eoff[u]);
        else w = kreg[u];
        float s0 = qb_s;
        s0 += q[0]*bflo(w.x) + q[1]*bfhi(w.x);
        s0 += q[2]*bflo(w.y) + q[3]*bfhi(w.y);
        s0 += q[4]*bflo(w.z) + q[5]*bfhi(w.z);
        s0 += q[6]*bflo(w.w) + q[7]*bfhi(w.w);
        s0 *= RSQRT_DM;
        ms[u] = s0;
        lmax = fmaxf(lmax, s0);
      } else ms[u] = -INFINITY;
    }
    #pragma unroll
    for (int off=32; off>0; off>>=1) lmax = fmaxf(lmax, __shfl_xor(lmax, off));
    if (lane==0) wred[wv] = lmax;
    __syncthreads();
    float mx = fmaxf(fmaxf(wred[0],wred[1]),fmaxf(wred[2],wred[3]));
    float lsum = 0.f;
    #pragma unroll
    for (int u=0; u<NU; u++) {
      int j = tid + u*256;
      if (FULL || j < J) {
        float e = __expf(ms[u]-mx);
        sc[j] = e;
        lsum += e;
      }
    }
    #pragma unroll
    for (int off=32; off>0; off>>=1) lsum += __shfl_xor(lsum, off);
    if (lane==0) wred[4+wv] = lsum;
    __syncthreads();
    float invZ = 1.f / (wred[4]+wred[5]+wred[6]+wred[7]);
    for (int m = wv; m < TOPM; m += 4) {
      float v = 0.f;
      #pragma unroll
      for (int jj = 0; jj < UNQ; jj += 64) {
        int j2 = jj + lane;
        if (UNQ % 64 == 0 || j2 < UNQ) v += sc[m*UNQ + j2];
      }
      #pragma unroll
      for (int off=32; off>0; off>>=1) v += __shfl_xor(v, off);
      if (lane==0) nws[((size_t)pb*SEQL + s)*TOPM + m] = v * invZ;
    }
    __syncthreads();
  }
}

// ---------------- fused back: scores | v-gather
__global__ __launch_bounds__(256) void k_back(const __hip_bfloat16* __restrict__ m0,
                                              const __hip_bfloat16* __restrict__ m1,
                                              const __hip_bfloat16* __restrict__ m2,
                                              const int* __restrict__ topm,
                                              const float* __restrict__ xmg,
                                              const float* __restrict__ cst,
                                              float* __restrict__ nws,
                                              const float* __restrict__ ydata,
                                              float* __restrict__ vbuf) {
  __shared__ float bpool[3968];
  int bid = blockIdx.x;
  if (bid < PB*24) {
    int pb = bid / 24, sg = bid - (bid/24)*24;
    int p = pb / BS;
    float* sc = bpool;
    int* tl = (int*)(bpool + 3840);
    float* wred = bpool + 3864;
    float* lcst = bpool + 3872;
    if (p == 0)
      scores_body<2>((const short*)m0, K0R, pb, sg, topm, xmg, cst, nws, sc, tl, wred, lcst);
    else if (p == 1)
      scores_body<1>((const short*)m1, K1R, pb, sg, topm, xmg, cst, nws, sc, tl, wred, lcst);
    else
      scores_body<0>((const short*)m2, K2R, pb, sg, topm, xmg, cst, nws, sc, tl, wred, lcst);
  } else {
    v_body(ydata, topm, vbuf, bid - PB*24, bpool);
  }
}

// ---------------- nw softmax over m, then out = sum_m nw[m] * v[m]
__global__ __launch_bounds__(256) void k_out(const float* __restrict__ nws,
                                             const float* __restrict__ vbuf,
                                             float* __restrict__ out) {
  __shared__ float nwp[TOPM];
  __shared__ float nwf[TOPM];
  int pb = blockIdx.x;
  int tid = threadIdx.x;
  if (tid < TOPM) {
    float s=0.f;
    for (int ss=0; ss<SEQL; ss++) s += nws[((size_t)pb*SEQL+ss)*TOPM + tid];
    nwp[tid] = s;
  }
  __syncthreads();
  if (tid==0) {
    float mx=-INFINITY;
    for (int m=0;m<TOPM;m++) mx=fmaxf(mx,nwp[m]);
    float Z=0.f;
    for (int m=0;m<TOPM;m++){ float e=expf(nwp[m]-mx); nwf[m]=e; Z+=e; }
    float iz=1.f/Z;
    for (int m=0;m<TOPM;m++) nwf[m]*=iz;
  }
  __syncthreads();
  for (int i=tid; i<PREDL*CH; i+=256) {
    float o=0.f;
    #pragma unroll
    for (int m=0;m<TOPM;m++) o += nwf[m]*vbuf[((size_t)pb*TOPM+m)*PREDL*CH + i];
    out[(size_t)pb*PREDL*CH + i] = o;
  }
}

extern "C" void kernel_launch(void* const* d_in, const int* in_sizes, int n_in,
                              void* d_out, int out_size, void* d_ws, size_t ws_size,
                              hipStream_t stream) {
  const float* x     = (const float*)d_in[0];
  const int*   index = (const int*)  d_in[1];
  const float* train = (const float*)d_in[2];
  const float* ydata = (const float*)d_in[3];
  const float* Wsim  = (const float*)d_in[4];
  const float* bsim  = (const float*)d_in[5];
  const float* Wq    = (const float*)d_in[6];
  const float* bq    = (const float*)d_in[7];
  const float* Wk    = (const float*)d_in[8];
  const float* bk    = (const float*)d_in[9];
  float* out = (float*)d_out;

  float* ws = (float*)d_ws;
  size_t off = 0;
  auto alloc = [&](size_t n)->float* { float* pp = ws + off; off += (n + 63) & ~(size_t)63; return pp; };
  __hip_bfloat16* m0b = (__hip_bfloat16*)alloc((size_t)NRP2*K0R/2);
  __hip_bfloat16* m1b = (__hip_bfloat16*)alloc((size_t)NRP2*K1R/2);
  __hip_bfloat16* m2b = (__hip_bfloat16*)alloc((size_t)NRP2*K2R/2);
  __hip_bfloat16* wt0 = (__hip_bfloat16*)alloc((size_t)FD*K0R/2);
  __hip_bfloat16* wt1 = (__hip_bfloat16*)alloc((size_t)FD*K1R/2);
  __hip_bfloat16* wt2 = (__hip_bfloat16*)alloc((size_t)FD*K2R/2);
  __hip_bfloat16* trH = (__hip_bfloat16*)alloc((size_t)NRP2*FD/2);
  __hip_bfloat16* trL = (__hip_bfloat16*)alloc((size_t)NRP2*FD/2);
  __hip_bfloat16* tadjH = (__hip_bfloat16*)alloc((size_t)128*FD/2);
  __hip_bfloat16* tadjL = (__hip_bfloat16*)alloc((size_t)128*FD/2);
  float* x_mg     = alloc((size_t)NPER*BS*FD);
  float* bx       = alloc((size_t)PB*FD);             // becomes u after k_bxnorm
  float* cpb      = alloc(PB);
  float* gpart    = alloc((size_t)KS*PB*FD);          // reused: bx partials, then t partials
  float* part     = alloc((size_t)NPER*NRP2*PCOLS);
  float* dotp3    = alloc((size_t)3*PB*NT);           // 11.5 MB: hh / hl / lh term planes
  float* cv       = alloc((size_t)PB*NCH*TOPM);
  int*   ci       = (int*)alloc(PB*NCH*TOPM);
  int*   topm     = (int*)alloc(PB*TOPM);
  float* cst      = alloc(128);
  float* vbuf     = alloc((size_t)PB*TOPM*PREDL*CH);
  float* nws      = alloc((size_t)PB*SEQL*TOPM);
  if (off * sizeof(float) > ws_size) return;          // insufficient scratch -> visible failure

  k_front<<<NT + NWTG + BS, 256, 0, stream>>>(x, train, x_mg, m0b, m1b, m2b, trH, trL,
                                              Wsim, wt0, wt1, wt2, Wq, bq, Wk, bk, cst);
  k_bx_part<<<dim3(24, KS), 256, 0, stream>>>(x_mg, Wsim, gpart);
  k_bxnorm<<<PB, 256, 0, stream>>>(gpart, bsim, bx, cpb);
  k_t_part<<<dim3(24, KS), 256, 0, stream>>>(bx, Wsim, gpart);
  k_tred_adj<<<PB, 192, 0, stream>>>(gpart, tadjH, tadjL);
  k_gemms<<<NB_DOT + 3*NWG2, 256, 0, stream>>>(m0b, m1b, m2b, wt0, wt1, wt2, bsim, part,
                                               tadjH, tadjL, trH, trL, dotp3);
  k_topk_part<<<dim3(PB, NCH), 256, 0, stream>>>(dotp3, cpb, part, index, cv, ci);
  k_topk_merge<<<PB, 64, 0, stream>>>(cv, ci, topm);
  k_back<<<PB*24 + PB*TOPM, 256, 0, stream>>>(m0b, m1b, m2b, topm, x_mg, cst, nws,
                                              ydata, vbuf);
  k_out<<<PB, 256, 0, stream>>>(nws, vbuf, out);
}

// Round 20
// 405.027 us; speedup vs baseline: 1.0033x; 1.0033x over previous
//
#include <hip/hip_runtime.h>
#include <hip/hip_bf16.h>
#include <math.h>

#define NPER 3
#define SEQL 192
#define PREDL 96
#define CH 8
#define FD 1536      // SEQL*CH
#define NT 10000
#define BS 32
#define PB 96        // NPER*BS
#define TOPM 20
#define DM 512
#define HALFW 287    // SEQ+PRED-1
#define NROWS 30000  // NPER*NT
#define NRP2 10112   // NT padded to 79*128
#define NRB2 79
#define NCB 12       // 1536/128 col blocks
#define PCOLS 24     // part slots per row: 12 col-blocks x 2 col-half waves
#define NWG2 (NRB2*NCB)   // 948 per plane
#define NJ 3840      // TOPM*SEQL
#define K0R 384      // reduced K, plane 0 (g=4)
#define K1R 768      // plane 1 (g=2)
#define K2R 1536     // plane 2 (g=1)
#define KS 16        // K-splits for bx/t small GEMMs
#define NCH 8        // top-k chunks
#define CHSZ (NT/NCH)
#define NWTG 4080    // wtg blocks: 85*48
#define NB_DOT (3*NRB2)  // 237 dot blocks: 3 error-split terms x 79 col strips
#define BUFSZ (2*128*32) // one pipeline buffer: A(8KB)+B(8KB) in shorts
#define RSQRT_DM 0.04419417382415922f

typedef __attribute__((ext_vector_type(8))) short bf16x8;
typedef __attribute__((ext_vector_type(4))) float f32x4;
typedef __attribute__((address_space(3))) short lds_short_t;
typedef __attribute__((address_space(1))) const short glb_short_t;

__device__ inline float bflo(unsigned u){ return __uint_as_float(u << 16); }
__device__ inline float bfhi(unsigned u){ return __uint_as_float(u & 0xFFFF0000u); }
__device__ inline float bf2f(unsigned short u){ return __uint_as_float((unsigned)u << 16); }
__device__ inline unsigned short f2bf(float v){
  __hip_bfloat16 h = __float2bfloat16(v);
  return *reinterpret_cast<unsigned short*>(&h);
}

// ---------------- decompose body (+ optional fused hi/lo split of the RAW row).
template<int L>
__device__ __forceinline__ void dec_body(const float* __restrict__ data,
                                         float* __restrict__ mg,
                                         __hip_bfloat16* __restrict__ m0,
                                         __hip_bfloat16* __restrict__ m1,
                                         __hip_bfloat16* __restrict__ m2,
                                         __hip_bfloat16* __restrict__ trH,
                                         __hip_bfloat16* __restrict__ trL,
                                         int N, int n, float* fpool) {
  float* row = fpool;               // L*CH = 1536
  float* m4  = fpool + L*CH;        // (L/4)*CH = 384
  float* m2s = fpool + L*CH + (L/4)*CH;  // (L/2)*CH = 768
  const float* src = data + (size_t)n*L*CH;
  for (int e = threadIdx.x; e < L*CH/4; e += 256)
    *reinterpret_cast<float4*>(&row[e*4]) = *reinterpret_cast<const float4*>(&src[e*4]);
  __syncthreads();
  for (int i = threadIdx.x; i < (L/4)*CH; i += 256) {
    int j = i >> 3, c = i & 7;
    m4[i] = (row[(4*j)*CH+c] + row[(4*j+1)*CH+c] + row[(4*j+2)*CH+c] + row[(4*j+3)*CH+c]) * 0.25f;
  }
  for (int i = threadIdx.x; i < (L/2)*CH; i += 256) {
    int j = i >> 3, c = i & 7;
    m2s[i] = (row[(2*j)*CH+c] + row[(2*j+1)*CH+c]) * 0.5f;
  }
  __syncthreads();
  if (mg) {
    size_t plane = (size_t)N*L*CH;
    size_t base  = (size_t)n*L*CH;
    for (int e = threadIdx.x; e < L*CH/4; e += 256) {
      int i = e*4;
      int l = i >> 3, c0 = i & 7;
      float v0[4], v1[4], v2[4];
      #pragma unroll
      for (int j=0;j<4;j++) {
        int c = c0 + j;
        v0[j] = m4[(l>>2)*CH+c] - m4[(L/4-1)*CH+c];
        v1[j] = m2s[(l>>1)*CH+c] - m2s[(L/2-1)*CH+c];
        v2[j] = row[i+j] - row[(L-1)*CH+c];
      }
      *reinterpret_cast<float4*>(&mg[base+i])           = make_float4(v0[0],v0[1],v0[2],v0[3]);
      *reinterpret_cast<float4*>(&mg[plane+base+i])     = make_float4(v1[0],v1[1],v1[2],v1[3]);
      *reinterpret_cast<float4*>(&mg[2*plane+base+i])   = make_float4(v2[0],v2[1],v2[2],v2[3]);
    }
  }
  if (m0) {
    unsigned short* p0 = (unsigned short*)m0 + (size_t)n*K0R;
    unsigned short* p1 = (unsigned short*)m1 + (size_t)n*K1R;
    unsigned short* p2 = (unsigned short*)m2 + (size_t)n*K2R;
    for (int e = threadIdx.x; e < K0R/4; e += 256) {
      int i = e*4, c0 = i & 7;
      ushort4 u;
      u.x = f2bf(m4[i]   - m4[(L/4-1)*CH + c0]);
      u.y = f2bf(m4[i+1] - m4[(L/4-1)*CH + c0+1]);
      u.z = f2bf(m4[i+2] - m4[(L/4-1)*CH + c0+2]);
      u.w = f2bf(m4[i+3] - m4[(L/4-1)*CH + c0+3]);
      *reinterpret_cast<ushort4*>(&p0[i]) = u;
    }
    for (int e = threadIdx.x; e < K1R/4; e += 256) {
      int i = e*4, c0 = i & 7;
      ushort4 u;
      u.x = f2bf(m2s[i]   - m2s[(L/2-1)*CH + c0]);
      u.y = f2bf(m2s[i+1] - m2s[(L/2-1)*CH + c0+1]);
      u.z = f2bf(m2s[i+2] - m2s[(L/2-1)*CH + c0+2]);
      u.w = f2bf(m2s[i+3] - m2s[(L/2-1)*CH + c0+3]);
      *reinterpret_cast<ushort4*>(&p1[i]) = u;
    }
    for (int e = threadIdx.x; e < K2R/4; e += 256) {
      int i = e*4, c0 = i & 7;
      ushort4 u;
      u.x = f2bf(row[i]   - row[(L-1)*CH + c0]);
      u.y = f2bf(row[i+1] - row[(L-1)*CH + c0+1]);
      u.z = f2bf(row[i+2] - row[(L-1)*CH + c0+2]);
      u.w = f2bf(row[i+3] - row[(L-1)*CH + c0+3]);
      *reinterpret_cast<ushort4*>(&p2[i]) = u;
    }
  }
  if (trH) {
    unsigned short* h = (unsigned short*)trH + (size_t)n*L*CH;
    unsigned short* l = (unsigned short*)trL + (size_t)n*L*CH;
    for (int e = threadIdx.x; e < L*CH/4; e += 256) {
      int i = e*4;
      ushort4 uh, ul;
      uh.x = f2bf(row[i]);   ul.x = f2bf(row[i]   - bf2f(uh.x));
      uh.y = f2bf(row[i+1]); ul.y = f2bf(row[i+1] - bf2f(uh.y));
      uh.z = f2bf(row[i+2]); ul.z = f2bf(row[i+2] - bf2f(uh.z));
      uh.w = f2bf(row[i+3]); ul.w = f2bf(row[i+3] - bf2f(uh.w));
      *reinterpret_cast<ushort4*>(&h[i]) = uh;
      *reinterpret_cast<ushort4*>(&l[i]) = ul;
    }
  }
}

// ---------------- group-summed transposed W builder + attention consts (bxx==84):
__device__ __forceinline__ void wtg_body(const float* __restrict__ W,
                                         __hip_bfloat16* __restrict__ wt0,
                                         __hip_bfloat16* __restrict__ wt1,
                                         __hip_bfloat16* __restrict__ wt2,
                                         const float* __restrict__ Wq,
                                         const float* __restrict__ bq,
                                         const float* __restrict__ Wk,
                                         const float* __restrict__ bk,
                                         float* __restrict__ cst,
                                         int wb, float* fpool) {
  int bxx = wb / 48, byy = wb % 48;
  if (bxx == 84) {
    if (byy != 0) return;
    int tt = threadIdx.x;
    if (tt < 64) {
      int c = tt >> 3, e = tt & 7;
      float s = 0.f;
      for (int d=0; d<DM; d++) s += Wq[c*DM+d] * Wk[e*DM+d];
      cst[tt] = s;
    } else if (tt < 72) {
      int c = tt - 64; float s=0.f;
      for (int d=0;d<DM;d++) s += Wq[c*DM+d]*bk[d];
      cst[tt] = s;
    } else if (tt < 80) {
      int e = tt - 72; float s=0.f;
      for (int d=0;d<DM;d++) s += Wk[e*DM+d]*bq[d];
      cst[tt] = s;
    } else if (tt == 80) {
      float s=0.f;
      for (int d=0;d<DM;d++) s += bq[d]*bk[d];
      cst[80] = s;
    }
    return;
  }
  int G, kr0, Kred;
  __hip_bfloat16* Wt;
  if (bxx < 12)      { G = 4; kr0 = bxx*32;      Kred = K0R; Wt = wt0; }
  else if (bxx < 36) { G = 2; kr0 = (bxx-12)*32; Kred = K1R; Wt = wt1; }
  else               { G = 1; kr0 = (bxx-36)*32; Kred = K2R; Wt = wt2; }
  int f0 = byy*32;
  int k0 = kr0*G;
  int tid = threadIdx.x, tx = tid & 31, ty = tid >> 5;
  for (int i = ty; i < 32*G; i += 8)
    fpool[i*33 + tx] = W[(size_t)(k0+i)*FD + f0 + tx];
  __syncthreads();
  for (int fl = ty; fl < 32; fl += 8) {
    float s = 0.f;
    for (int i=0;i<G;i++) s += fpool[(((tx>>3)*G+i)*8 + (tx&7))*33 + fl];
    Wt[(size_t)(f0+fl)*Kred + kr0 + tx] = __float2bfloat16(s);
  }
}

// ---------------- fused front: decompose(train) | wtg+consts | decompose(x)
__global__ __launch_bounds__(256) void k_front(const float* __restrict__ x,
                                               const float* __restrict__ train,
                                               float* __restrict__ x_mg,
                                               __hip_bfloat16* __restrict__ m0,
                                               __hip_bfloat16* __restrict__ m1,
                                               __hip_bfloat16* __restrict__ m2,
                                               __hip_bfloat16* __restrict__ trH,
                                               __hip_bfloat16* __restrict__ trL,
                                               const float* __restrict__ W,
                                               __hip_bfloat16* __restrict__ wt0,
                                               __hip_bfloat16* __restrict__ wt1,
                                               __hip_bfloat16* __restrict__ wt2,
                                               const float* __restrict__ Wq,
                                               const float* __restrict__ bq,
                                               const float* __restrict__ Wk,
                                               const float* __restrict__ bk,
                                               float* __restrict__ cst) {
  __shared__ float fpool[128*33];
  int bid = blockIdx.x;
  if (bid < NT) {
    dec_body<SEQL>(train, nullptr, m0, m1, m2, trH, trL, NT, bid, fpool);
  } else if (bid < NT + NWTG) {
    wtg_body(W, wt0, wt1, wt2, Wq, bq, Wk, bk, cst, bid - NT, fpool);
  } else {
    dec_body<SEQL>(x, x_mg, nullptr, nullptr, nullptr, nullptr, nullptr,
                   BS, bid - NT - NWTG, fpool);
  }
}

// ---------------- bx partial: bxp[ks][pb][f] = sum over K-slice of x_mg[pb] @ W (96 x 1536)
__global__ __launch_bounds__(256) void k_bx_part(const float* __restrict__ xmg,
                                                 const float* __restrict__ W,
                                                 float* __restrict__ bxp) {
  __shared__ float xs[PB][17];
  __shared__ float Ws[16][65];
  int f0 = blockIdx.x * 64;
  int ks = blockIdx.y;
  int kbase = ks * (FD/KS);
  int tid = threadIdx.x;
  int fl = tid & 63, gp = tid >> 6;
  float acc[24];
  #pragma unroll
  for (int j=0;j<24;j++) acc[j]=0.f;
  for (int k0 = kbase; k0 < kbase + FD/KS; k0 += 16) {
    for (int e = tid; e < PB*16; e += 256) {
      int r = e >> 4, k = e & 15;
      xs[r][k] = xmg[(size_t)r*FD + k0 + k];
    }
    for (int e = tid; e < 16*64; e += 256) {
      int k = e >> 6, f = e & 63;
      Ws[k][f] = W[(size_t)(k0+k)*FD + f0 + f];
    }
    __syncthreads();
    #pragma unroll
    for (int kk = 0; kk < 16; kk++) {
      float w = Ws[kk][fl];
      #pragma unroll
      for (int j=0;j<24;j++) acc[j] += w * xs[gp + 4*j][kk];
    }
    __syncthreads();
  }
  #pragma unroll
  for (int j=0;j<24;j++) {
    int pb = gp + 4*j;
    bxp[((size_t)ks*PB + pb)*FD + f0 + fl] = acc[j];
  }
}

// ---------------- fused: reduce bx partials + bias -> row; l2-normalize -> u; cpb = <u,b>
__global__ __launch_bounds__(256) void k_bxnorm(const float* __restrict__ bxp,
                                                const float* __restrict__ bsim,
                                                float* __restrict__ u_out,
                                                float* __restrict__ cpb) {
  __shared__ float rowv[FD];
  __shared__ float r1[256], r2[256];
  __shared__ float invs;
  int pb = blockIdx.x, tid = threadIdx.x;
  float s2 = 0.f, sb = 0.f;
  for (int f = tid; f < FD; f += 256) {
    float s = 0.f;
    #pragma unroll
    for (int ks=0; ks<KS; ks++) s += bxp[((size_t)ks*PB + pb)*FD + f];
    s += bsim[f];
    rowv[f] = s;
    s2 += s*s; sb += s*bsim[f];
  }
  r1[tid]=s2; r2[tid]=sb; __syncthreads();
  for (int off=128; off>0; off>>=1) {
    if (tid<off) { r1[tid]+=r1[tid+off]; r2[tid]+=r2[tid+off]; }
    __syncthreads();
  }
  if (tid==0) {
    float iv = 1.f / fmaxf(sqrtf(r1[0]), 1e-12f);
    invs = iv;
    cpb[pb] = r2[0] * iv;
  }
  __syncthreads();
  float iv = invs;
  for (int f = tid; f < FD; f += 256) u_out[(size_t)pb*FD + f] = rowv[f]*iv;
}

// ---------------- t partial: tp[ks][pb][k] = sum over f-slice of W[k][f]*u[pb][f]
__global__ __launch_bounds__(256) void k_t_part(const float* __restrict__ u,
                                                const float* __restrict__ W,
                                                float* __restrict__ tp) {
  __shared__ float us[PB][17];
  __shared__ float Wt[64][17];
  int k0 = blockIdx.x * 64;
  int ks = blockIdx.y;
  int fbase = ks * (FD/KS);
  int tid = threadIdx.x;
  int kl = tid & 63, gp = tid >> 6;
  float acc[24];
  #pragma unroll
  for (int j=0;j<24;j++) acc[j]=0.f;
  for (int fc = fbase; fc < fbase + FD/KS; fc += 16) {
    for (int e = tid; e < PB*16; e += 256) {
      int r = e >> 4, f = e & 15;
      us[r][f] = u[(size_t)r*FD + fc + f];
    }
    for (int e = tid; e < 64*16; e += 256) {
      int k = e >> 4, f = e & 15;
      Wt[k][f] = W[(size_t)(k0+k)*FD + fc + f];
    }
    __syncthreads();
    #pragma unroll
    for (int ff = 0; ff < 16; ff++) {
      float w = Wt[kl][ff];
      #pragma unroll
      for (int j=0;j<24;j++) acc[j] += w * us[gp + 4*j][ff];
    }
    __syncthreads();
  }
  #pragma unroll
  for (int j=0;j<24;j++) {
    int pb = gp + 4*j;
    tp[((size_t)ks*PB + pb)*FD + k0 + kl] = acc[j];
  }
}

// ---------------- fused: reduce t partials -> ts; decompose-adjoint -> tadj (bf16 hi/lo split)
__global__ __launch_bounds__(192) void k_tred_adj(const float* __restrict__ tp,
                                                  __hip_bfloat16* __restrict__ tadjH,
                                                  __hip_bfloat16* __restrict__ tadjL) {
  __shared__ float ts[SEQL*CH];
  __shared__ float Tc[CH];
  int pb = blockIdx.x;
  int p = pb / BS;
  int g = (p==0) ? 4 : (p==1) ? 2 : 1;
  int l = threadIdx.x;
  #pragma unroll
  for (int c=0;c<CH;c++) {
    float s = 0.f;
    #pragma unroll
    for (int ks=0; ks<KS; ks++) s += tp[((size_t)ks*PB + pb)*FD + l*CH + c];
    ts[l*CH+c] = s;
  }
  __syncthreads();
  if (l < CH) {
    float s=0.f;
    for (int j=0;j<SEQL;j++) s += ts[j*CH+l];
    Tc[l] = s;
  }
  __syncthreads();
  int j0 = (l/g)*g;
  bool last = (j0 == SEQL-g);
  float ig = 1.f/(float)g;
  unsigned short* th = (unsigned short*)tadjH;
  unsigned short* tl = (unsigned short*)tadjL;
  #pragma unroll
  for (int c=0;c<CH;c++) {
    float s = 0.f;
    for (int jj=0;jj<g;jj++) s += ts[(j0+jj)*CH+c];
    float v = s*ig - (last ? Tc[c]*ig : 0.f);
    unsigned short hv = f2bf(v);
    th[(size_t)pb*FD + l*CH+c] = hv;
    tl[(size_t)pb*FD + l*CH+c] = f2bf(v - bf2f(hv));
  }
}

// ---------------- pipelined staging helpers (T3+T4: counted vmcnt, barrier w/o drain)
#define PIPE_SYNC_4()  do { asm volatile("s_waitcnt vmcnt(4)" ::: "memory"); \
                            __builtin_amdgcn_s_barrier(); \
                            __builtin_amdgcn_sched_barrier(0); } while(0)
#define PIPE_SYNC_0()  do { asm volatile("s_waitcnt vmcnt(0)" ::: "memory"); \
                            __builtin_amdgcn_s_barrier(); \
                            __builtin_amdgcn_sched_barrier(0); } while(0)

// ---------------- norm GEMM body, 3-buffer counted-vmcnt pipeline (depth 2)
__device__ __forceinline__ void norm_body(const short* __restrict__ A,
                                          const short* __restrict__ B,
                                          int K, int p, int seg,
                                          const float* __restrict__ bsim,
                                          float* __restrict__ part,
                                          short* pool) {
  int q = NWG2 >> 3, r = NWG2 & 7;
  int xcd = seg & 7, pos = seg >> 3;
  int wgid = (xcd < r ? xcd*(q+1) : r*(q+1) + (xcd-r)*q) + pos;
  int rb = wgid / NCB, cb = wgid - rb*NCB;
  int row0 = rb*128, col0 = cb*128;
  int tid = threadIdx.x, lane = tid & 63, wid = tid >> 6;
  int wr = (wid>>1)*64, wc = (wid&1)*64;

  size_t aoff[2], boff[2];
  int ldsb[2];
  #pragma unroll
  for (int i=0;i<2;i++) {
    int lrow = (wid*2+i)*16 + (lane>>2);
    int sl = lane & 3;
    int ss = (sl - lrow - (lrow>>2)) & 3;
    aoff[i] = (size_t)(row0 + lrow)*K + 8*ss;
    boff[i] = (size_t)(col0 + lrow)*K + 8*ss;
    ldsb[i] = (wid*2+i)*16*32;
  }

  f32x4 acc[4][4];
  #pragma unroll
  for (int m=0;m<4;m++)
    #pragma unroll
    for (int n=0;n<4;n++) acc[m][n] = (f32x4){0.f,0.f,0.f,0.f};

  int kslot = lane >> 4;
  int nt = K >> 5;
  #pragma unroll
  for (int i=0;i<2;i++) {
    __builtin_amdgcn_global_load_lds((glb_short_t*)(A + aoff[i]),
                                     (lds_short_t*)&pool[ldsb[i]], 16, 0, 0);
    __builtin_amdgcn_global_load_lds((glb_short_t*)(B + boff[i]),
                                     (lds_short_t*)&pool[128*32 + ldsb[i]], 16, 0, 0);
  }
  #pragma unroll
  for (int i=0;i<2;i++) {
    __builtin_amdgcn_global_load_lds((glb_short_t*)(A + aoff[i] + 32),
                                     (lds_short_t*)&pool[BUFSZ + ldsb[i]], 16, 0, 0);
    __builtin_amdgcn_global_load_lds((glb_short_t*)(B + boff[i] + 32),
                                     (lds_short_t*)&pool[BUFSZ + 128*32 + ldsb[i]], 16, 0, 0);
  }
  PIPE_SYNC_4();
  int cur = 0;
  for (int t = 0; t < nt; ++t) {
    if (t + 2 < nt) {
      int nx = cur + 2; if (nx >= 3) nx -= 3;
      short* nb = pool + nx*BUFSZ;
      int kn = (t+2) << 5;
      #pragma unroll
      for (int i=0;i<2;i++) {
        __builtin_amdgcn_global_load_lds((glb_short_t*)(A + aoff[i] + kn),
                                         (lds_short_t*)&nb[ldsb[i]], 16, 0, 0);
        __builtin_amdgcn_global_load_lds((glb_short_t*)(B + boff[i] + kn),
                                         (lds_short_t*)&nb[128*32 + ldsb[i]], 16, 0, 0);
      }
    }
    const short* lA = pool + cur*BUFSZ;
    const short* lB = lA + 128*32;
    bf16x8 af[4], bfr[4];
    #pragma unroll
    for (int m=0;m<4;m++) {
      int rr = wr + m*16 + (lane&15);
      int s = (kslot + rr + (rr>>2)) & 3;
      af[m] = *(const bf16x8*)&lA[rr*32 + s*8];
    }
    #pragma unroll
    for (int n=0;n<4;n++) {
      int rr = wc + n*16 + (lane&15);
      int s = (kslot + rr + (rr>>2)) & 3;
      bfr[n] = *(const bf16x8*)&lB[rr*32 + s*8];
    }
    #pragma unroll
    for (int m=0;m<4;m++)
      #pragma unroll
      for (int n=0;n<4;n++)
        acc[m][n] = __builtin_amdgcn_mfma_f32_16x16x32_bf16(af[m], bfr[n], acc[m][n], 0, 0, 0);
    if (t + 1 < nt) {
      if (t + 2 < nt) PIPE_SYNC_4(); else PIPE_SYNC_0();
    }
    cur = (cur + 1 == 3) ? 0 : cur + 1;
  }

  float bv[4];
  #pragma unroll
  for (int n=0;n<4;n++) bv[n] = bsim[col0 + wc + n*16 + (lane&15)];
  int pslot = cb*2 + (wid&1);
  #pragma unroll
  for (int m=0;m<4;m++) {
    #pragma unroll
    for (int j=0;j<4;j++) {
      float s = 0.f;
      #pragma unroll
      for (int n=0;n<4;n++) { float v = acc[m][n][j] + bv[n]; s += v*v; }
      s += __shfl_xor(s, 1); s += __shfl_xor(s, 2);
      s += __shfl_xor(s, 4); s += __shfl_xor(s, 8);
      if ((lane & 15) == 0) {
        int rr = row0 + wr + m*16 + (lane>>4)*4 + j;
        part[((size_t)p*NRP2 + rr)*PCOLS + pslot] = s;
      }
    }
  }
}

// ---------------- single-term dot GEMM body, same 3-buffer counted-vmcnt pipeline
__device__ __forceinline__ void dot_body(const short* __restrict__ A,
                                         const short* __restrict__ B,
                                         float* __restrict__ dst,
                                         int cbn, short* pool) {
  int col0 = cbn * 128;
  int tid = threadIdx.x, lane = tid & 63, wid = tid >> 6;
  int wr = (wid>>1)*64, wc = (wid&1)*64;

  size_t aoff[2], boff[2];
  int ldsb[2];
  #pragma unroll
  for (int i=0;i<2;i++) {
    int lrow = (wid*2+i)*16 + (lane>>2);
    int sl = lane & 3;
    int ss = (sl - lrow - (lrow>>2)) & 3;
    aoff[i] = (size_t)lrow*FD + 8*ss;
    boff[i] = (size_t)(col0 + lrow)*FD + 8*ss;
    ldsb[i] = (wid*2+i)*16*32;
  }

  f32x4 acc[4][4];
  #pragma unroll
  for (int m=0;m<4;m++)
    #pragma unroll
    for (int n=0;n<4;n++) acc[m][n] = (f32x4){0.f,0.f,0.f,0.f};

  int kslot = lane >> 4;
  const int nt = FD >> 5;
  #pragma unroll
  for (int i=0;i<2;i++) {
    __builtin_amdgcn_global_load_lds((glb_short_t*)(A + aoff[i]),
                                     (lds_short_t*)&pool[ldsb[i]], 16, 0, 0);
    __builtin_amdgcn_global_load_lds((glb_short_t*)(B + boff[i]),
                                     (lds_short_t*)&pool[128*32 + ldsb[i]], 16, 0, 0);
  }
  #pragma unroll
  for (int i=0;i<2;i++) {
    __builtin_amdgcn_global_load_lds((glb_short_t*)(A + aoff[i] + 32),
                                     (lds_short_t*)&pool[BUFSZ + ldsb[i]], 16, 0, 0);
    __builtin_amdgcn_global_load_lds((glb_short_t*)(B + boff[i] + 32),
                                     (lds_short_t*)&pool[BUFSZ + 128*32 + ldsb[i]], 16, 0, 0);
  }
  PIPE_SYNC_4();
  int cur = 0;
  for (int t = 0; t < nt; ++t) {
    if (t + 2 < nt) {
      int nx = cur + 2; if (nx >= 3) nx -= 3;
      short* nb = pool + nx*BUFSZ;
      int kn = (t+2) << 5;
      #pragma unroll
      for (int i=0;i<2;i++) {
        __builtin_amdgcn_global_load_lds((glb_short_t*)(A + aoff[i] + kn),
                                         (lds_short_t*)&nb[ldsb[i]], 16, 0, 0);
        __builtin_amdgcn_global_load_lds((glb_short_t*)(B + boff[i] + kn),
                                         (lds_short_t*)&nb[128*32 + ldsb[i]], 16, 0, 0);
      }
    }
    const short* lA = pool + cur*BUFSZ;
    const short* lB = lA + 128*32;
    bf16x8 af[4], bfr[4];
    #pragma unroll
    for (int m=0;m<4;m++) {
      int rr = wr + m*16 + (lane&15);
      int s = (kslot + rr + (rr>>2)) & 3;
      af[m] = *(const bf16x8*)&lA[rr*32 + s*8];
    }
    #pragma unroll
    for (int n=0;n<4;n++) {
      int rr = wc + n*16 + (lane&15);
      int s = (kslot + rr + (rr>>2)) & 3;
      bfr[n] = *(const bf16x8*)&lB[rr*32 + s*8];
    }
    #pragma unroll
    for (int m=0;m<4;m++)
      #pragma unroll
      for (int n=0;n<4;n++)
        acc[m][n] = __builtin_amdgcn_mfma_f32_16x16x32_bf16(af[m], bfr[n], acc[m][n], 0, 0, 0);
    if (t + 1 < nt) {
      if (t + 2 < nt) PIPE_SYNC_4(); else PIPE_SYNC_0();
    }
    cur = (cur + 1 == 3) ? 0 : cur + 1;
  }

  #pragma unroll
  for (int m=0;m<4;m++) {
    int prow = wr + m*16 + (lane>>4)*4;
    if (prow >= PB) continue;
    #pragma unroll
    for (int n=0;n<4;n++) {
      int ncol = col0 + wc + n*16 + (lane&15);
      if (ncol >= NT) continue;
      #pragma unroll
      for (int j=0;j<4;j++) {
        dst[(size_t)(prow + j)*NT + ncol] = acc[m][n][j];
      }
    }
  }
}

// ---------------- fused GEMMs, uniform 48 KB 3-buf pool. LPT: dot terms | p2 | p1 | p0
__global__ __launch_bounds__(256) void k_gemms(
    const __hip_bfloat16* __restrict__ A0b, const __hip_bfloat16* __restrict__ A1b,
    const __hip_bfloat16* __restrict__ A2b,
    const __hip_bfloat16* __restrict__ B0b, const __hip_bfloat16* __restrict__ B1b,
    const __hip_bfloat16* __restrict__ B2b,
    const float* __restrict__ bsim, float* __restrict__ part,
    const __hip_bfloat16* __restrict__ tadjHb, const __hip_bfloat16* __restrict__ tadjLb,
    const __hip_bfloat16* __restrict__ trHb, const __hip_bfloat16* __restrict__ trLb,
    float* __restrict__ dotp3) {
  __shared__ __align__(16) short pool[3*BUFSZ];
  int bid = blockIdx.x;
  if (bid < NB_DOT) {
    int term = bid / NRB2, cbn = bid - term*NRB2;
    const short* A = (term == 2) ? (const short*)tadjLb : (const short*)tadjHb;
    const short* B = (term == 1) ? (const short*)trLb   : (const short*)trHb;
    dot_body(A, B, dotp3 + (size_t)term*PB*NT, cbn, pool);
  } else if (bid < NB_DOT + NWG2) {
    norm_body((const short*)A2b, (const short*)B2b, K2R, 2, bid - NB_DOT, bsim, part, pool);
  } else if (bid < NB_DOT + 2*NWG2) {
    norm_body((const short*)A1b, (const short*)B1b, K1R, 1, bid - NB_DOT - NWG2, bsim, part, pool);
  } else {
    norm_body((const short*)A0b, (const short*)B0b, K0R, 0,
              bid - NB_DOT - 2*NWG2, bsim, part, pool);
  }
}

// ---------------- norm2[r] = sum of 24 part slots (sequential order -> bit-identical)
__global__ __launch_bounds__(256) void k_norm_red(const float* __restrict__ part,
                                                  float* __restrict__ norm2) {
  int r = blockIdx.x*256 + threadIdx.x;
  if (r < NROWS) {
    int p = r / NT, rr = r - p*NT;
    float s=0.f;
    #pragma unroll
    for (int cb=0; cb<PCOLS; cb++) s += part[((size_t)p*NRP2 + rr)*PCOLS + cb];
    norm2[r] = s;
  }
}

// ---------------- top-20 phase A: per-(pb, chunk) local top-20 (exact; tie -> lower index)
__global__ __launch_bounds__(256) void k_topk_part(const float* __restrict__ dotp3,
                                                   const float* __restrict__ cpb,
                                                   const float* __restrict__ norm2,
                                                   const int* __restrict__ index,
                                                   float* __restrict__ cv,
                                                   int* __restrict__ ci) {
  __shared__ float vals[CHSZ];
  __shared__ float rv[4];
  __shared__ int   ri[4];
  int pb = blockIdx.x, ch = blockIdx.y;
  int p = pb / BS, b = pb - p*BS;
  int n0 = ch*CHSZ;
  int tid = threadIdx.x, lane = tid & 63, wv = tid >> 6;
  int idx = index[b];
  int bl = idx - HALFW; if (bl < 0) bl = 0;
  int bh = idx + HALFW; if (bh > NT-1) bh = NT-1;
  const float* n2 = norm2 + (size_t)p*NT;
  float cp = cpb[pb];
  for (int i = tid; i < CHSZ; i += 256) {
    int n = n0 + i;
    float d = dotp3[(size_t)pb*NT + n]
            + dotp3[(size_t)PB*NT + (size_t)pb*NT + n]
            + dotp3[2*(size_t)PB*NT + (size_t)pb*NT + n] + cp;
    float v = d / fmaxf(sqrtf(n2[n]), 1e-12f);
    if (n >= bl && n <= bh) v = -INFINITY;
    vals[i] = v;
  }
  __syncthreads();
  for (int it = 0; it < TOPM; it++) {
    float bv = -INFINITY; int bi = CHSZ;
    for (int i = tid; i < CHSZ; i += 256) {
      float v = vals[i];
      if (v > bv) { bv = v; bi = i; }
    }
    #pragma unroll
    for (int off=32; off>0; off>>=1) {
      float ov = __shfl_xor(bv, off);
      int   oi = __shfl_xor(bi, off);
      if (ov > bv || (ov == bv && oi < bi)) { bv = ov; bi = oi; }
    }
    if (lane == 0) { rv[wv] = bv; ri[wv] = bi; }
    __syncthreads();
    if (tid == 0) {
      float fv = rv[0]; int fi = ri[0];
      #pragma unroll
      for (int w2=1; w2<4; w2++)
        if (rv[w2] > fv || (rv[w2] == fv && ri[w2] < fi)) { fv = rv[w2]; fi = ri[w2]; }
      cv[(pb*NCH + ch)*TOPM + it] = fv;
      ci[(pb*NCH + ch)*TOPM + it] = n0 + fi;
      vals[fi] = -INFINITY;
    }
    __syncthreads();
  }
}

// ---------------- top-20 phase B: merge NCH x 20 candidates (exact; tie -> lower global index)
__global__ __launch_bounds__(64) void k_topk_merge(const float* __restrict__ cv,
                                                   const int* __restrict__ ci,
                                                   int* __restrict__ topm) {
  __shared__ float v[NCH*TOPM];
  __shared__ int   id[NCH*TOPM];
  int pb = blockIdx.x;
  int lane = threadIdx.x;
  for (int i = lane; i < NCH*TOPM; i += 64) {
    v[i]  = cv[pb*NCH*TOPM + i];
    id[i] = ci[pb*NCH*TOPM + i];
  }
  __syncthreads();
  for (int it = 0; it < TOPM; it++) {
    float bv = -INFINITY; int bi = 0x7fffffff;
    for (int i = lane; i < NCH*TOPM; i += 64) {
      float vv = v[i];
      int ii = id[i];
      if (vv > bv || (vv == bv && ii < bi)) { bv = vv; bi = ii; }
    }
    #pragma unroll
    for (int off=32; off>0; off>>=1) {
      float ov = __shfl_xor(bv, off);
      int   oi = __shfl_xor(bi, off);
      if (ov > bv || (ov == bv && oi < bi)) { bv = ov; bi = oi; }
    }
    if (lane == 0) topm[pb*TOPM + it] = bi;
    for (int i = lane; i < NCH*TOPM; i += 64)
      if (id[i] == bi) v[i] = -INFINITY;
    __syncthreads();
  }
}

// ---------------- v body: gathered y_mg rows
__device__ __forceinline__ void v_body(const float* __restrict__ ydata,
                                       const int* __restrict__ topm,
                                       float* __restrict__ vbuf,
                                       int bm, float* bpool) {
  float* row = bpool;          // 768
  float* m4  = bpool + 768;    // 192
  float* m2  = bpool + 960;    // 384
  int pb = bm / TOPM;
  int p = pb / BS;
  int n = topm[bm];
  int tid = threadIdx.x;
  const float* src = ydata + (size_t)n*PREDL*CH;
  for (int i=tid; i<PREDL*CH; i+=256) row[i]=src[i];
  __syncthreads();
  for (int i=tid; i<(PREDL/4)*CH; i+=256) {
    int j=i>>3, c=i&7;
    m4[i] = (row[(4*j)*CH+c]+row[(4*j+1)*CH+c]+row[(4*j+2)*CH+c]+row[(4*j+3)*CH+c])*0.25f;
  }
  for (int i=tid; i<(PREDL/2)*CH; i+=256) {
    int j=i>>3, c=i&7;
    m2[i] = (row[(2*j)*CH+c]+row[(2*j+1)*CH+c])*0.5f;
  }
  __syncthreads();
  float* dst = vbuf + (size_t)bm*PREDL*CH;
  for (int i=tid; i<PREDL*CH; i+=256) {
    int l=i>>3, c=i&7;
    float v;
    if (p==0)      v = m4[(l>>2)*CH+c] - m4[(PREDL/4-1)*CH+c];
    else if (p==1) v = m2[(l>>1)*CH+c] - m2[(PREDL/2-1)*CH+c];
    else           v = row[i] - row[(PREDL-1)*CH+c];
    dst[i] = v;
  }
}

// ---------------- scores body, group-collapsed per plane (hoisted kreg, R18-verified form)
template<int SH>
__device__ __forceinline__ void scores_body(
    const short* __restrict__ plane, int Kp,
    int pb, int sg,
    const int* __restrict__ topm,
    const float* __restrict__ xmg,
    const float* __restrict__ cst,
    float* __restrict__ nws,
    float* sc, int* tl, float* wred, float* lcst) {
  constexpr int UNQ = SEQL >> SH;      // 48 / 96 / 192
  constexpr int J   = TOPM * UNQ;      // 960 / 1920 / 3840
  constexpr int NU  = (J + 255) >> 8;  // 4 / 8 / 15
  constexpr bool FULL = (J % 256 == 0);
  int tid = threadIdx.x;
  int lane = tid & 63, wv = tid >> 6;
  if (tid < TOPM) tl[tid] = topm[pb*TOPM + tid];
  if (tid >= 32 && tid < 32+81) lcst[tid-32] = cst[tid-32];
  __syncthreads();
  uint4 kreg[NU];
  #pragma unroll
  for (int u=0; u<NU; u++) {
    int j = tid + u*256;
    if (FULL || j < J) {
      int m = j / UNQ, jj = j - m*UNQ;
      kreg[u] = *reinterpret_cast<const uint4*>(plane + (size_t)tl[m]*Kp + jj*8);
    }
  }
  for (int s8 = 0; s8 < 8; s8++) {
    int s = sg*8 + s8;
    int qr = pb*SEQL + s;
    float4 qa = *reinterpret_cast<const float4*>(&xmg[(size_t)qr*8]);
    float4 qc = *reinterpret_cast<const float4*>(&xmg[(size_t)qr*8+4]);
    float xq[8] = {qa.x,qa.y,qa.z,qa.w,qc.x,qc.y,qc.z,qc.w};
    float q[8];
    #pragma unroll
    for (int e=0;e<8;e++) {
      float ss = lcst[72+e];
      #pragma unroll
      for (int c=0;c<8;c++) ss += xq[c]*lcst[c*8+e];
      q[e] = ss;
    }
    float qb_s = lcst[80];
    #pragma unroll
    for (int c=0;c<8;c++) qb_s += xq[c]*lcst[64+c];
    float ms[NU];
    float lmax = -INFINITY;
    #pragma unroll
    for (int u=0; u<NU; u++) {
      int j = tid + u*256;
      if (FULL || j < J) {
        uint4 w = kreg[u];
        float s0 = qb_s;
        s0 += q[0]*bflo(w.x) + q[1]*bfhi(w.x);
        s0 += q[2]*bflo(w.y) + q[3]*bfhi(w.y);
        s0 += q[4]*bflo(w.z) + q[5]*bfhi(w.z);
        s0 += q[6]*bflo(w.w) + q[7]*bfhi(w.w);
        s0 *= RSQRT_DM;
        ms[u] = s0;
        lmax = fmaxf(lmax, s0);
      } else ms[u] = -INFINITY;
    }
    #pragma unroll
    for (int off=32; off>0; off>>=1) lmax = fmaxf(lmax, __shfl_xor(lmax, off));
    if (lane==0) wred[wv] = lmax;
    __syncthreads();
    float mx = fmaxf(fmaxf(wred[0],wred[1]),fmaxf(wred[2],wred[3]));
    float lsum = 0.f;
    #pragma unroll
    for (int u=0; u<NU; u++) {
      int j = tid + u*256;
      if (FULL || j < J) {
        float e = __expf(ms[u]-mx);
        sc[j] = e;
        lsum += e;
      }
    }
    #pragma unroll
    for (int off=32; off>0; off>>=1) lsum += __shfl_xor(lsum, off);
    if (lane==0) wred[4+wv] = lsum;
    __syncthreads();
    float invZ = 1.f / (wred[4]+wred[5]+wred[6]+wred[7]);
    for (int m = wv; m < TOPM; m += 4) {
      float v = 0.f;
      #pragma unroll
      for (int jj = 0; jj < UNQ; jj += 64) {
        int j2 = jj + lane;
        if (UNQ % 64 == 0 || j2 < UNQ) v += sc[m*UNQ + j2];
      }
      #pragma unroll
      for (int off=32; off>0; off>>=1) v += __shfl_xor(v, off);
      if (lane==0) nws[((size_t)pb*SEQL + s)*TOPM + m] = v * invZ;
    }
    __syncthreads();
  }
}

// ---------------- fused back: scores | v-gather
__global__ __launch_bounds__(256) void k_back(const __hip_bfloat16* __restrict__ m0,
                                              const __hip_bfloat16* __restrict__ m1,
                                              const __hip_bfloat16* __restrict__ m2,
                                              const int* __restrict__ topm,
                                              const float* __restrict__ xmg,
                                              const float* __restrict__ cst,
                                              float* __restrict__ nws,
                                              const float* __restrict__ ydata,
                                              float* __restrict__ vbuf) {
  __shared__ float bpool[3968];
  int bid = blockIdx.x;
  if (bid < PB*24) {
    int pb = bid / 24, sg = bid - (bid/24)*24;
    int p = pb / BS;
    float* sc = bpool;
    int* tl = (int*)(bpool + 3840);
    float* wred = bpool + 3864;
    float* lcst = bpool + 3872;
    if (p == 0)
      scores_body<2>((const short*)m0, K0R, pb, sg, topm, xmg, cst, nws, sc, tl, wred, lcst);
    else if (p == 1)
      scores_body<1>((const short*)m1, K1R, pb, sg, topm, xmg, cst, nws, sc, tl, wred, lcst);
    else
      scores_body<0>((const short*)m2, K2R, pb, sg, topm, xmg, cst, nws, sc, tl, wred, lcst);
  } else {
    v_body(ydata, topm, vbuf, bid - PB*24, bpool);
  }
}

// ---------------- nw softmax over m, then out = sum_m nw[m] * v[m]
__global__ __launch_bounds__(256) void k_out(const float* __restrict__ nws,
                                             const float* __restrict__ vbuf,
                                             float* __restrict__ out) {
  __shared__ float nwp[TOPM];
  __shared__ float nwf[TOPM];
  int pb = blockIdx.x;
  int tid = threadIdx.x;
  if (tid < TOPM) {
    float s=0.f;
    for (int ss=0; ss<SEQL; ss++) s += nws[((size_t)pb*SEQL+ss)*TOPM + tid];
    nwp[tid] = s;
  }
  __syncthreads();
  if (tid==0) {
    float mx=-INFINITY;
    for (int m=0;m<TOPM;m++) mx=fmaxf(mx,nwp[m]);
    float Z=0.f;
    for (int m=0;m<TOPM;m++){ float e=expf(nwp[m]-mx); nwf[m]=e; Z+=e; }
    float iz=1.f/Z;
    for (int m=0;m<TOPM;m++) nwf[m]*=iz;
  }
  __syncthreads();
  for (int i=tid; i<PREDL*CH; i+=256) {
    float o=0.f;
    #pragma unroll
    for (int m=0;m<TOPM;m++) o += nwf[m]*vbuf[((size_t)pb*TOPM+m)*PREDL*CH + i];
    out[(size_t)pb*PREDL*CH + i] = o;
  }
}

extern "C" void kernel_launch(void* const* d_in, const int* in_sizes, int n_in,
                              void* d_out, int out_size, void* d_ws, size_t ws_size,
                              hipStream_t stream) {
  const float* x     = (const float*)d_in[0];
  const int*   index = (const int*)  d_in[1];
  const float* train = (const float*)d_in[2];
  const float* ydata = (const float*)d_in[3];
  const float* Wsim  = (const float*)d_in[4];
  const float* bsim  = (const float*)d_in[5];
  const float* Wq    = (const float*)d_in[6];
  const float* bq    = (const float*)d_in[7];
  const float* Wk    = (const float*)d_in[8];
  const float* bk    = (const float*)d_in[9];
  float* out = (float*)d_out;

  float* ws = (float*)d_ws;
  size_t off = 0;
  auto alloc = [&](size_t n)->float* { float* pp = ws + off; off += (n + 63) & ~(size_t)63; return pp; };
  __hip_bfloat16* m0b = (__hip_bfloat16*)alloc((size_t)NRP2*K0R/2);
  __hip_bfloat16* m1b = (__hip_bfloat16*)alloc((size_t)NRP2*K1R/2);
  __hip_bfloat16* m2b = (__hip_bfloat16*)alloc((size_t)NRP2*K2R/2);
  __hip_bfloat16* wt0 = (__hip_bfloat16*)alloc((size_t)FD*K0R/2);
  __hip_bfloat16* wt1 = (__hip_bfloat16*)alloc((size_t)FD*K1R/2);
  __hip_bfloat16* wt2 = (__hip_bfloat16*)alloc((size_t)FD*K2R/2);
  __hip_bfloat16* trH = (__hip_bfloat16*)alloc((size_t)NRP2*FD/2);
  __hip_bfloat16* trL = (__hip_bfloat16*)alloc((size_t)NRP2*FD/2);
  __hip_bfloat16* tadjH = (__hip_bfloat16*)alloc((size_t)128*FD/2);
  __hip_bfloat16* tadjL = (__hip_bfloat16*)alloc((size_t)128*FD/2);
  float* x_mg     = alloc((size_t)NPER*BS*FD);
  float* bx       = alloc((size_t)PB*FD);             // becomes u after k_bxnorm
  float* cpb      = alloc(PB);
  float* gpart    = alloc((size_t)KS*PB*FD);          // reused: bx partials, then t partials
  float* part     = alloc((size_t)NPER*NRP2*PCOLS);
  float* norm2    = alloc(NROWS);
  float* dotp3    = alloc((size_t)3*PB*NT);           // 11.5 MB: hh / hl / lh term planes
  float* cv       = alloc((size_t)PB*NCH*TOPM);
  int*   ci       = (int*)alloc(PB*NCH*TOPM);
  int*   topm     = (int*)alloc(PB*TOPM);
  float* cst      = alloc(128);
  float* vbuf     = alloc((size_t)PB*TOPM*PREDL*CH);
  float* nws      = alloc((size_t)PB*SEQL*TOPM);
  if (off * sizeof(float) > ws_size) return;          // insufficient scratch -> visible failure

  k_front<<<NT + NWTG + BS, 256, 0, stream>>>(x, train, x_mg, m0b, m1b, m2b, trH, trL,
                                              Wsim, wt0, wt1, wt2, Wq, bq, Wk, bk, cst);
  k_bx_part<<<dim3(24, KS), 256, 0, stream>>>(x_mg, Wsim, gpart);
  k_bxnorm<<<PB, 256, 0, stream>>>(gpart, bsim, bx, cpb);
  k_t_part<<<dim3(24, KS), 256, 0, stream>>>(bx, Wsim, gpart);
  k_tred_adj<<<PB, 192, 0, stream>>>(gpart, tadjH, tadjL);
  k_gemms<<<NB_DOT + 3*NWG2, 256, 0, stream>>>(m0b, m1b, m2b, wt0, wt1, wt2, bsim, part,
                                               tadjH, tadjL, trH, trL, dotp3);
  k_norm_red<<<(NROWS+255)/256, 256, 0, stream>>>(part, norm2);
  k_topk_part<<<dim3(PB, NCH), 256, 0, stream>>>(dotp3, cpb, norm2, index, cv, ci);
  k_topk_merge<<<PB, 64, 0, stream>>>(cv, ci, topm);
  k_back<<<PB*24 + PB*TOPM, 256, 0, stream>>>(m0b, m1b, m2b, topm, x_mg, cst, nws,
                                              ydata, vbuf);
  k_out<<<PB, 256, 0, stream>>>(nws, vbuf, out);
}

// Round 21
// 385.017 us; speedup vs baseline: 1.0554x; 1.0520x over previous
//
#include <hip/hip_runtime.h>
#include <hip/hip_bf16.h>
#include <math.h>

#define NPER 3
#define SEQL 192
#define PREDL 96
#define CH 8
#define FD 1536      // SEQL*CH
#define NT 10000
#define BS 32
#define PB 96        // NPER*BS
#define TOPM 20
#define DM 512
#define HALFW 287    // SEQ+PRED-1
#define NROWS 30000  // NPER*NT
#define NRP3 10240   // NT padded to 40*256
#define NRB3 40      // 256-row blocks per plane
#define NCB3 6       // 1536/256 col blocks
#define PCOLS 24     // part slots per row: 6 col-blocks x 4 col-quarter waves (same 64-col groups)
#define NWG3 (NRB3*NCB3)  // 240 per plane
#define NRB2 79      // dot 128-col strips over NT
#define K0R 384      // reduced K, plane 0 (g=4)
#define K1R 768      // plane 1 (g=2)
#define K2R 1536     // plane 2 (g=1)
#define KS 16        // K-splits for bx/t small GEMMs
#define NCH 8        // top-k chunks
#define CHSZ (NT/NCH)
#define NWTG 4080    // wtg blocks: 85*48
#define NB_DOT (3*NRB2)  // 237 dot blocks: 3 error-split terms x 79 col strips
#define BUFSZ3 (2*256*32)  // norm buffer: A(16KB)+B(16KB) in shorts
#define BUFSZD (2*128*32)  // dot buffer: A(8KB)+B(8KB) in shorts
#define RSQRT_DM 0.04419417382415922f

typedef __attribute__((ext_vector_type(8))) short bf16x8;
typedef __attribute__((ext_vector_type(4))) float f32x4;
typedef __attribute__((address_space(3))) short lds_short_t;
typedef __attribute__((address_space(1))) const short glb_short_t;

__device__ inline float bflo(unsigned u){ return __uint_as_float(u << 16); }
__device__ inline float bfhi(unsigned u){ return __uint_as_float(u & 0xFFFF0000u); }
__device__ inline float bf2f(unsigned short u){ return __uint_as_float((unsigned)u << 16); }
__device__ inline unsigned short f2bf(float v){
  __hip_bfloat16 h = __float2bfloat16(v);
  return *reinterpret_cast<unsigned short*>(&h);
}

// ---------------- decompose body (+ optional fused hi/lo split of the RAW row).
template<int L>
__device__ __forceinline__ void dec_body(const float* __restrict__ data,
                                         float* __restrict__ mg,
                                         __hip_bfloat16* __restrict__ m0,
                                         __hip_bfloat16* __restrict__ m1,
                                         __hip_bfloat16* __restrict__ m2,
                                         __hip_bfloat16* __restrict__ trH,
                                         __hip_bfloat16* __restrict__ trL,
                                         int N, int n, float* fpool) {
  float* row = fpool;               // L*CH = 1536
  float* m4  = fpool + L*CH;        // (L/4)*CH = 384
  float* m2s = fpool + L*CH + (L/4)*CH;  // (L/2)*CH = 768
  const float* src = data + (size_t)n*L*CH;
  for (int e = threadIdx.x; e < L*CH/4; e += 256)
    *reinterpret_cast<float4*>(&row[e*4]) = *reinterpret_cast<const float4*>(&src[e*4]);
  __syncthreads();
  for (int i = threadIdx.x; i < (L/4)*CH; i += 256) {
    int j = i >> 3, c = i & 7;
    m4[i] = (row[(4*j)*CH+c] + row[(4*j+1)*CH+c] + row[(4*j+2)*CH+c] + row[(4*j+3)*CH+c]) * 0.25f;
  }
  for (int i = threadIdx.x; i < (L/2)*CH; i += 256) {
    int j = i >> 3, c = i & 7;
    m2s[i] = (row[(2*j)*CH+c] + row[(2*j+1)*CH+c]) * 0.5f;
  }
  __syncthreads();
  if (mg) {
    size_t plane = (size_t)N*L*CH;
    size_t base  = (size_t)n*L*CH;
    for (int e = threadIdx.x; e < L*CH/4; e += 256) {
      int i = e*4;
      int l = i >> 3, c0 = i & 7;
      float v0[4], v1[4], v2[4];
      #pragma unroll
      for (int j=0;j<4;j++) {
        int c = c0 + j;
        v0[j] = m4[(l>>2)*CH+c] - m4[(L/4-1)*CH+c];
        v1[j] = m2s[(l>>1)*CH+c] - m2s[(L/2-1)*CH+c];
        v2[j] = row[i+j] - row[(L-1)*CH+c];
      }
      *reinterpret_cast<float4*>(&mg[base+i])           = make_float4(v0[0],v0[1],v0[2],v0[3]);
      *reinterpret_cast<float4*>(&mg[plane+base+i])     = make_float4(v1[0],v1[1],v1[2],v1[3]);
      *reinterpret_cast<float4*>(&mg[2*plane+base+i])   = make_float4(v2[0],v2[1],v2[2],v2[3]);
    }
  }
  if (m0) {
    unsigned short* p0 = (unsigned short*)m0 + (size_t)n*K0R;
    unsigned short* p1 = (unsigned short*)m1 + (size_t)n*K1R;
    unsigned short* p2 = (unsigned short*)m2 + (size_t)n*K2R;
    for (int e = threadIdx.x; e < K0R/4; e += 256) {
      int i = e*4, c0 = i & 7;
      ushort4 u;
      u.x = f2bf(m4[i]   - m4[(L/4-1)*CH + c0]);
      u.y = f2bf(m4[i+1] - m4[(L/4-1)*CH + c0+1]);
      u.z = f2bf(m4[i+2] - m4[(L/4-1)*CH + c0+2]);
      u.w = f2bf(m4[i+3] - m4[(L/4-1)*CH + c0+3]);
      *reinterpret_cast<ushort4*>(&p0[i]) = u;
    }
    for (int e = threadIdx.x; e < K1R/4; e += 256) {
      int i = e*4, c0 = i & 7;
      ushort4 u;
      u.x = f2bf(m2s[i]   - m2s[(L/2-1)*CH + c0]);
      u.y = f2bf(m2s[i+1] - m2s[(L/2-1)*CH + c0+1]);
      u.z = f2bf(m2s[i+2] - m2s[(L/2-1)*CH + c0+2]);
      u.w = f2bf(m2s[i+3] - m2s[(L/2-1)*CH + c0+3]);
      *reinterpret_cast<ushort4*>(&p1[i]) = u;
    }
    for (int e = threadIdx.x; e < K2R/4; e += 256) {
      int i = e*4, c0 = i & 7;
      ushort4 u;
      u.x = f2bf(row[i]   - row[(L-1)*CH + c0]);
      u.y = f2bf(row[i+1] - row[(L-1)*CH + c0+1]);
      u.z = f2bf(row[i+2] - row[(L-1)*CH + c0+2]);
      u.w = f2bf(row[i+3] - row[(L-1)*CH + c0+3]);
      *reinterpret_cast<ushort4*>(&p2[i]) = u;
    }
  }
  if (trH) {
    unsigned short* h = (unsigned short*)trH + (size_t)n*L*CH;
    unsigned short* l = (unsigned short*)trL + (size_t)n*L*CH;
    for (int e = threadIdx.x; e < L*CH/4; e += 256) {
      int i = e*4;
      ushort4 uh, ul;
      uh.x = f2bf(row[i]);   ul.x = f2bf(row[i]   - bf2f(uh.x));
      uh.y = f2bf(row[i+1]); ul.y = f2bf(row[i+1] - bf2f(uh.y));
      uh.z = f2bf(row[i+2]); ul.z = f2bf(row[i+2] - bf2f(uh.z));
      uh.w = f2bf(row[i+3]); ul.w = f2bf(row[i+3] - bf2f(uh.w));
      *reinterpret_cast<ushort4*>(&h[i]) = uh;
      *reinterpret_cast<ushort4*>(&l[i]) = ul;
    }
  }
}

// ---------------- group-summed transposed W builder + attention consts (bxx==84):
__device__ __forceinline__ void wtg_body(const float* __restrict__ W,
                                         __hip_bfloat16* __restrict__ wt0,
                                         __hip_bfloat16* __restrict__ wt1,
                                         __hip_bfloat16* __restrict__ wt2,
                                         const float* __restrict__ Wq,
                                         const float* __restrict__ bq,
                                         const float* __restrict__ Wk,
                                         const float* __restrict__ bk,
                                         float* __restrict__ cst,
                                         int wb, float* fpool) {
  int bxx = wb / 48, byy = wb % 48;
  if (bxx == 84) {
    if (byy != 0) return;
    int tt = threadIdx.x;
    if (tt < 64) {
      int c = tt >> 3, e = tt & 7;
      float s = 0.f;
      for (int d=0; d<DM; d++) s += Wq[c*DM+d] * Wk[e*DM+d];
      cst[tt] = s;
    } else if (tt < 72) {
      int c = tt - 64; float s=0.f;
      for (int d=0;d<DM;d++) s += Wq[c*DM+d]*bk[d];
      cst[tt] = s;
    } else if (tt < 80) {
      int e = tt - 72; float s=0.f;
      for (int d=0;d<DM;d++) s += Wk[e*DM+d]*bq[d];
      cst[tt] = s;
    } else if (tt == 80) {
      float s=0.f;
      for (int d=0;d<DM;d++) s += bq[d]*bk[d];
      cst[80] = s;
    }
    return;
  }
  int G, kr0, Kred;
  __hip_bfloat16* Wt;
  if (bxx < 12)      { G = 4; kr0 = bxx*32;      Kred = K0R; Wt = wt0; }
  else if (bxx < 36) { G = 2; kr0 = (bxx-12)*32; Kred = K1R; Wt = wt1; }
  else               { G = 1; kr0 = (bxx-36)*32; Kred = K2R; Wt = wt2; }
  int f0 = byy*32;
  int k0 = kr0*G;
  int tid = threadIdx.x, tx = tid & 31, ty = tid >> 5;
  for (int i = ty; i < 32*G; i += 8)
    fpool[i*33 + tx] = W[(size_t)(k0+i)*FD + f0 + tx];
  __syncthreads();
  for (int fl = ty; fl < 32; fl += 8) {
    float s = 0.f;
    for (int i=0;i<G;i++) s += fpool[(((tx>>3)*G+i)*8 + (tx&7))*33 + fl];
    Wt[(size_t)(f0+fl)*Kred + kr0 + tx] = __float2bfloat16(s);
  }
}

// ---------------- fused front: decompose(train) | wtg+consts | decompose(x)
__global__ __launch_bounds__(256) void k_front(const float* __restrict__ x,
                                               const float* __restrict__ train,
                                               float* __restrict__ x_mg,
                                               __hip_bfloat16* __restrict__ m0,
                                               __hip_bfloat16* __restrict__ m1,
                                               __hip_bfloat16* __restrict__ m2,
                                               __hip_bfloat16* __restrict__ trH,
                                               __hip_bfloat16* __restrict__ trL,
                                               const float* __restrict__ W,
                                               __hip_bfloat16* __restrict__ wt0,
                                               __hip_bfloat16* __restrict__ wt1,
                                               __hip_bfloat16* __restrict__ wt2,
                                               const float* __restrict__ Wq,
                                               const float* __restrict__ bq,
                                               const float* __restrict__ Wk,
                                               const float* __restrict__ bk,
                                               float* __restrict__ cst) {
  __shared__ float fpool[128*33];
  int bid = blockIdx.x;
  if (bid < NT) {
    dec_body<SEQL>(train, nullptr, m0, m1, m2, trH, trL, NT, bid, fpool);
  } else if (bid < NT + NWTG) {
    wtg_body(W, wt0, wt1, wt2, Wq, bq, Wk, bk, cst, bid - NT, fpool);
  } else {
    dec_body<SEQL>(x, x_mg, nullptr, nullptr, nullptr, nullptr, nullptr,
                   BS, bid - NT - NWTG, fpool);
  }
}

// ---------------- bx partial: bxp[ks][pb][f] = sum over K-slice of x_mg[pb] @ W (96 x 1536)
__global__ __launch_bounds__(256) void k_bx_part(const float* __restrict__ xmg,
                                                 const float* __restrict__ W,
                                                 float* __restrict__ bxp) {
  __shared__ float xs[PB][17];
  __shared__ float Ws[16][65];
  int f0 = blockIdx.x * 64;
  int ks = blockIdx.y;
  int kbase = ks * (FD/KS);
  int tid = threadIdx.x;
  int fl = tid & 63, gp = tid >> 6;
  float acc[24];
  #pragma unroll
  for (int j=0;j<24;j++) acc[j]=0.f;
  for (int k0 = kbase; k0 < kbase + FD/KS; k0 += 16) {
    for (int e = tid; e < PB*16; e += 256) {
      int r = e >> 4, k = e & 15;
      xs[r][k] = xmg[(size_t)r*FD + k0 + k];
    }
    for (int e = tid; e < 16*64; e += 256) {
      int k = e >> 6, f = e & 63;
      Ws[k][f] = W[(size_t)(k0+k)*FD + f0 + f];
    }
    __syncthreads();
    #pragma unroll
    for (int kk = 0; kk < 16; kk++) {
      float w = Ws[kk][fl];
      #pragma unroll
      for (int j=0;j<24;j++) acc[j] += w * xs[gp + 4*j][kk];
    }
    __syncthreads();
  }
  #pragma unroll
  for (int j=0;j<24;j++) {
    int pb = gp + 4*j;
    bxp[((size_t)ks*PB + pb)*FD + f0 + fl] = acc[j];
  }
}

// ---------------- fused: reduce bx partials + bias -> row; l2-normalize -> u; cpb = <u,b>
__global__ __launch_bounds__(256) void k_bxnorm(const float* __restrict__ bxp,
                                                const float* __restrict__ bsim,
                                                float* __restrict__ u_out,
                                                float* __restrict__ cpb) {
  __shared__ float rowv[FD];
  __shared__ float r1[256], r2[256];
  __shared__ float invs;
  int pb = blockIdx.x, tid = threadIdx.x;
  float s2 = 0.f, sb = 0.f;
  for (int f = tid; f < FD; f += 256) {
    float s = 0.f;
    #pragma unroll
    for (int ks=0; ks<KS; ks++) s += bxp[((size_t)ks*PB + pb)*FD + f];
    s += bsim[f];
    rowv[f] = s;
    s2 += s*s; sb += s*bsim[f];
  }
  r1[tid]=s2; r2[tid]=sb; __syncthreads();
  for (int off=128; off>0; off>>=1) {
    if (tid<off) { r1[tid]+=r1[tid+off]; r2[tid]+=r2[tid+off]; }
    __syncthreads();
  }
  if (tid==0) {
    float iv = 1.f / fmaxf(sqrtf(r1[0]), 1e-12f);
    invs = iv;
    cpb[pb] = r2[0] * iv;
  }
  __syncthreads();
  float iv = invs;
  for (int f = tid; f < FD; f += 256) u_out[(size_t)pb*FD + f] = rowv[f]*iv;
}

// ---------------- t partial: tp[ks][pb][k] = sum over f-slice of W[k][f]*u[pb][f]
__global__ __launch_bounds__(256) void k_t_part(const float* __restrict__ u,
                                                const float* __restrict__ W,
                                                float* __restrict__ tp) {
  __shared__ float us[PB][17];
  __shared__ float Wt[64][17];
  int k0 = blockIdx.x * 64;
  int ks = blockIdx.y;
  int fbase = ks * (FD/KS);
  int tid = threadIdx.x;
  int kl = tid & 63, gp = tid >> 6;
  float acc[24];
  #pragma unroll
  for (int j=0;j<24;j++) acc[j]=0.f;
  for (int fc = fbase; fc < fbase + FD/KS; fc += 16) {
    for (int e = tid; e < PB*16; e += 256) {
      int r = e >> 4, f = e & 15;
      us[r][f] = u[(size_t)r*FD + fc + f];
    }
    for (int e = tid; e < 64*16; e += 256) {
      int k = e >> 4, f = e & 15;
      Wt[k][f] = W[(size_t)(k0+k)*FD + fc + f];
    }
    __syncthreads();
    #pragma unroll
    for (int ff = 0; ff < 16; ff++) {
      float w = Wt[kl][ff];
      #pragma unroll
      for (int j=0;j<24;j++) acc[j] += w * us[gp + 4*j][ff];
    }
    __syncthreads();
  }
  #pragma unroll
  for (int j=0;j<24;j++) {
    int pb = gp + 4*j;
    tp[((size_t)ks*PB + pb)*FD + k0 + kl] = acc[j];
  }
}

// ---------------- fused: reduce t partials -> ts; decompose-adjoint -> tadj (bf16 hi/lo split)
__global__ __launch_bounds__(192) void k_tred_adj(const float* __restrict__ tp,
                                                  __hip_bfloat16* __restrict__ tadjH,
                                                  __hip_bfloat16* __restrict__ tadjL) {
  __shared__ float ts[SEQL*CH];
  __shared__ float Tc[CH];
  int pb = blockIdx.x;
  int p = pb / BS;
  int g = (p==0) ? 4 : (p==1) ? 2 : 1;
  int l = threadIdx.x;
  #pragma unroll
  for (int c=0;c<CH;c++) {
    float s = 0.f;
    #pragma unroll
    for (int ks=0; ks<KS; ks++) s += tp[((size_t)ks*PB + pb)*FD + l*CH + c];
    ts[l*CH+c] = s;
  }
  __syncthreads();
  if (l < CH) {
    float s=0.f;
    for (int j=0;j<SEQL;j++) s += ts[j*CH+l];
    Tc[l] = s;
  }
  __syncthreads();
  int j0 = (l/g)*g;
  bool last = (j0 == SEQL-g);
  float ig = 1.f/(float)g;
  unsigned short* th = (unsigned short*)tadjH;
  unsigned short* tl = (unsigned short*)tadjL;
  #pragma unroll
  for (int c=0;c<CH;c++) {
    float s = 0.f;
    for (int jj=0;jj<g;jj++) s += ts[(j0+jj)*CH+c];
    float v = s*ig - (last ? Tc[c]*ig : 0.f);
    unsigned short hv = f2bf(v);
    th[(size_t)pb*FD + l*CH+c] = hv;
    tl[(size_t)pb*FD + l*CH+c] = f2bf(v - bf2f(hv));
  }
}

// ---------------- pipelined staging helpers (T3+T4: counted vmcnt, barrier w/o drain)
#define PIPE_SYNC_4()  do { asm volatile("s_waitcnt vmcnt(4)" ::: "memory"); \
                            __builtin_amdgcn_s_barrier(); \
                            __builtin_amdgcn_sched_barrier(0); } while(0)
#define PIPE_SYNC_2()  do { asm volatile("s_waitcnt vmcnt(2)" ::: "memory"); \
                            __builtin_amdgcn_s_barrier(); \
                            __builtin_amdgcn_sched_barrier(0); } while(0)
#define PIPE_SYNC_0()  do { asm volatile("s_waitcnt vmcnt(0)" ::: "memory"); \
                            __builtin_amdgcn_s_barrier(); \
                            __builtin_amdgcn_sched_barrier(0); } while(0)

// ---------------- norm GEMM body, 256x256 tile, 512 threads (8 waves 2Mx4N, each 128x64),
// 3-buffer counted-vmcnt pipeline (depth 2). Same swizzle involution & K order as the
// verified 128^2 body; per-64-col partial slots map to the same column groups in the same
// order -> part values bit-identical to the 128^2 version.
__device__ __forceinline__ void norm_body(const short* __restrict__ A,
                                          const short* __restrict__ B,
                                          int K, int p, int seg,
                                          const float* __restrict__ bsim,
                                          float* __restrict__ part,
                                          short* pool) {
  int q = NWG3 >> 3, r = NWG3 & 7;   // 30, 0 -> bijective
  int xcd = seg & 7, pos = seg >> 3;
  int wgid = (xcd < r ? xcd*(q+1) : r*(q+1) + (xcd-r)*q) + pos;
  int rb = wgid / NCB3, cb = wgid - rb*NCB3;
  int row0 = rb*256, col0 = cb*256;
  int tid = threadIdx.x, lane = tid & 63, wid = tid >> 6;
  int wm = wid >> 2, wn = wid & 3;   // 2 x 4 wave grid

  size_t aoff[2], boff[2];
  int ldsA[2], ldsB[2];
  #pragma unroll
  for (int i=0;i<2;i++) {
    int lrow = (i*8 + wid)*16 + (lane>>2);   // 0..255 over i,wid
    int sl = lane & 3;
    int ss = (sl - lrow - (lrow>>2)) & 3;
    aoff[i] = (size_t)(row0 + lrow)*K + 8*ss;
    boff[i] = (size_t)(col0 + lrow)*K + 8*ss;
    ldsA[i] = (i*8 + wid)*16*32;
    ldsB[i] = 256*32 + (i*8 + wid)*16*32;
  }

  f32x4 acc[8][4];
  #pragma unroll
  for (int m=0;m<8;m++)
    #pragma unroll
    for (int n=0;n<4;n++) acc[m][n] = (f32x4){0.f,0.f,0.f,0.f};

  int kslot = lane >> 4;
  int nt = K >> 5;
  // prologue: stage t=0 (buf0) and t=1 (buf1)
  #pragma unroll
  for (int i=0;i<2;i++) {
    __builtin_amdgcn_global_load_lds((glb_short_t*)(A + aoff[i]),
                                     (lds_short_t*)&pool[ldsA[i]], 16, 0, 0);
    __builtin_amdgcn_global_load_lds((glb_short_t*)(B + boff[i]),
                                     (lds_short_t*)&pool[ldsB[i]], 16, 0, 0);
  }
  #pragma unroll
  for (int i=0;i<2;i++) {
    __builtin_amdgcn_global_load_lds((glb_short_t*)(A + aoff[i] + 32),
                                     (lds_short_t*)&pool[BUFSZ3 + ldsA[i]], 16, 0, 0);
    __builtin_amdgcn_global_load_lds((glb_short_t*)(B + boff[i] + 32),
                                     (lds_short_t*)&pool[BUFSZ3 + ldsB[i]], 16, 0, 0);
  }
  PIPE_SYNC_4();
  int cur = 0;
  for (int t = 0; t < nt; ++t) {
    if (t + 2 < nt) {
      int nx = cur + 2; if (nx >= 3) nx -= 3;
      short* nb = pool + nx*BUFSZ3;
      int kn = (t+2) << 5;
      #pragma unroll
      for (int i=0;i<2;i++) {
        __builtin_amdgcn_global_load_lds((glb_short_t*)(A + aoff[i] + kn),
                                         (lds_short_t*)&nb[ldsA[i]], 16, 0, 0);
        __builtin_amdgcn_global_load_lds((glb_short_t*)(B + boff[i] + kn),
                                         (lds_short_t*)&nb[ldsB[i]], 16, 0, 0);
      }
    }
    const short* lA = pool + cur*BUFSZ3;
    const short* lB = lA + 256*32;
    bf16x8 af[8], bfr[4];
    #pragma unroll
    for (int m=0;m<8;m++) {
      int rr = wm*128 + m*16 + (lane&15);
      int s = (kslot + rr + (rr>>2)) & 3;
      af[m] = *(const bf16x8*)&lA[rr*32 + s*8];
    }
    #pragma unroll
    for (int n=0;n<4;n++) {
      int rr = wn*64 + n*16 + (lane&15);
      int s = (kslot + rr + (rr>>2)) & 3;
      bfr[n] = *(const bf16x8*)&lB[rr*32 + s*8];
    }
    #pragma unroll
    for (int m=0;m<8;m++)
      #pragma unroll
      for (int n=0;n<4;n++)
        acc[m][n] = __builtin_amdgcn_mfma_f32_16x16x32_bf16(af[m], bfr[n], acc[m][n], 0, 0, 0);
    if (t + 1 < nt) {
      if (t + 2 < nt) PIPE_SYNC_4(); else PIPE_SYNC_0();
    }
    cur = (cur + 1 == 3) ? 0 : cur + 1;
  }

  float bv[4];
  #pragma unroll
  for (int n=0;n<4;n++) bv[n] = bsim[col0 + wn*64 + n*16 + (lane&15)];
  int pslot = cb*4 + wn;   // same 64-col groups as before: slot = col/64
  #pragma unroll
  for (int m=0;m<8;m++) {
    #pragma unroll
    for (int j=0;j<4;j++) {
      float s = 0.f;
      #pragma unroll
      for (int n=0;n<4;n++) { float v = acc[m][n][j] + bv[n]; s += v*v; }
      s += __shfl_xor(s, 1); s += __shfl_xor(s, 2);
      s += __shfl_xor(s, 4); s += __shfl_xor(s, 8);
      if ((lane & 15) == 0) {
        int rr = row0 + wm*128 + m*16 + (lane>>4)*4 + j;
        part[((size_t)p*NRP3 + rr)*PCOLS + pslot] = s;
      }
    }
  }
}

// ---------------- single-term dot GEMM body, 128x128 tile @512 threads (8 waves 2Mx4N,
// each 64x32), 3-buffer counted-vmcnt pipeline (2 loads/thread/iter -> vmcnt(2)).
__device__ __forceinline__ void dot_body(const short* __restrict__ A,
                                         const short* __restrict__ B,
                                         float* __restrict__ dst,
                                         int cbn, short* pool) {
  int col0 = cbn * 128;
  int tid = threadIdx.x, lane = tid & 63, wid = tid >> 6;
  int wm = wid >> 2, wn = wid & 3;

  int lrow = wid*16 + (lane>>2);          // 0..127
  int sl = lane & 3;
  int ss = (sl - lrow - (lrow>>2)) & 3;
  size_t aoff = (size_t)lrow*FD + 8*ss;
  size_t boff = (size_t)(col0 + lrow)*FD + 8*ss;
  int ldsA = wid*16*32;
  int ldsB = 128*32 + wid*16*32;

  f32x4 acc[4][2];
  #pragma unroll
  for (int m=0;m<4;m++)
    #pragma unroll
    for (int n=0;n<2;n++) acc[m][n] = (f32x4){0.f,0.f,0.f,0.f};

  int kslot = lane >> 4;
  const int nt = FD >> 5;
  __builtin_amdgcn_global_load_lds((glb_short_t*)(A + aoff),
                                   (lds_short_t*)&pool[ldsA], 16, 0, 0);
  __builtin_amdgcn_global_load_lds((glb_short_t*)(B + boff),
                                   (lds_short_t*)&pool[ldsB], 16, 0, 0);
  __builtin_amdgcn_global_load_lds((glb_short_t*)(A + aoff + 32),
                                   (lds_short_t*)&pool[BUFSZD + ldsA], 16, 0, 0);
  __builtin_amdgcn_global_load_lds((glb_short_t*)(B + boff + 32),
                                   (lds_short_t*)&pool[BUFSZD + ldsB], 16, 0, 0);
  PIPE_SYNC_2();
  int cur = 0;
  for (int t = 0; t < nt; ++t) {
    if (t + 2 < nt) {
      int nx = cur + 2; if (nx >= 3) nx -= 3;
      short* nb = pool + nx*BUFSZD;
      int kn = (t+2) << 5;
      __builtin_amdgcn_global_load_lds((glb_short_t*)(A + aoff + kn),
                                       (lds_short_t*)&nb[ldsA], 16, 0, 0);
      __builtin_amdgcn_global_load_lds((glb_short_t*)(B + boff + kn),
                                       (lds_short_t*)&nb[ldsB], 16, 0, 0);
    }
    const short* lA = pool + cur*BUFSZD;
    const short* lB = lA + 128*32;
    bf16x8 af[4], bfr[2];
    #pragma unroll
    for (int m=0;m<4;m++) {
      int rr = wm*64 + m*16 + (lane&15);
      int s = (kslot + rr + (rr>>2)) & 3;
      af[m] = *(const bf16x8*)&lA[rr*32 + s*8];
    }
    #pragma unroll
    for (int n=0;n<2;n++) {
      int rr = wn*32 + n*16 + (lane&15);
      int s = (kslot + rr + (rr>>2)) & 3;
      bfr[n] = *(const bf16x8*)&lB[rr*32 + s*8];
    }
    #pragma unroll
    for (int m=0;m<4;m++)
      #pragma unroll
      for (int n=0;n<2;n++)
        acc[m][n] = __builtin_amdgcn_mfma_f32_16x16x32_bf16(af[m], bfr[n], acc[m][n], 0, 0, 0);
    if (t + 1 < nt) {
      if (t + 2 < nt) PIPE_SYNC_2(); else PIPE_SYNC_0();
    }
    cur = (cur + 1 == 3) ? 0 : cur + 1;
  }

  #pragma unroll
  for (int m=0;m<4;m++) {
    int prow = wm*64 + m*16 + (lane>>4)*4;
    if (prow >= PB) continue;
    #pragma unroll
    for (int n=0;n<2;n++) {
      int ncol = col0 + wn*32 + n*16 + (lane&15);
      if (ncol >= NT) continue;
      #pragma unroll
      for (int j=0;j<4;j++) {
        dst[(size_t)(prow + j)*NT + ncol] = acc[m][n][j];
      }
    }
  }
}

// ---------------- fused GEMMs, 512 threads, 96 KB 3-buf pool. LPT: p2 | p1 | dot | p0
__global__ __launch_bounds__(512, 2) void k_gemms(
    const __hip_bfloat16* __restrict__ A0b, const __hip_bfloat16* __restrict__ A1b,
    const __hip_bfloat16* __restrict__ A2b,
    const __hip_bfloat16* __restrict__ B0b, const __hip_bfloat16* __restrict__ B1b,
    const __hip_bfloat16* __restrict__ B2b,
    const float* __restrict__ bsim, float* __restrict__ part,
    const __hip_bfloat16* __restrict__ tadjHb, const __hip_bfloat16* __restrict__ tadjLb,
    const __hip_bfloat16* __restrict__ trHb, const __hip_bfloat16* __restrict__ trLb,
    float* __restrict__ dotp3) {
  __shared__ __align__(16) short pool[3*BUFSZ3];
  int bid = blockIdx.x;
  if (bid < NWG3) {
    norm_body((const short*)A2b, (const short*)B2b, K2R, 2, bid, bsim, part, pool);
  } else if (bid < 2*NWG3) {
    norm_body((const short*)A1b, (const short*)B1b, K1R, 1, bid - NWG3, bsim, part, pool);
  } else if (bid < 2*NWG3 + NB_DOT) {
    int d = bid - 2*NWG3;
    int term = d / NRB2, cbn = d - term*NRB2;
    const short* A = (term == 2) ? (const short*)tadjLb : (const short*)tadjHb;
    const short* B = (term == 1) ? (const short*)trLb   : (const short*)trHb;
    dot_body(A, B, dotp3 + (size_t)term*PB*NT, cbn, pool);
  } else {
    norm_body((const short*)A0b, (const short*)B0b, K0R, 0,
              bid - 2*NWG3 - NB_DOT, bsim, part, pool);
  }
}

// ---------------- norm2[r] = sum of 24 part slots (sequential order -> bit-identical)
__global__ __launch_bounds__(256) void k_norm_red(const float* __restrict__ part,
                                                  float* __restrict__ norm2) {
  int r = blockIdx.x*256 + threadIdx.x;
  if (r < NROWS) {
    int p = r / NT, rr = r - p*NT;
    float s=0.f;
    #pragma unroll
    for (int cb=0; cb<PCOLS; cb++) s += part[((size_t)p*NRP3 + rr)*PCOLS + cb];
    norm2[r] = s;
  }
}

// ---------------- top-20 phase A: per-(pb, chunk) local top-20 (exact; tie -> lower index)
__global__ __launch_bounds__(256) void k_topk_part(const float* __restrict__ dotp3,
                                                   const float* __restrict__ cpb,
                                                   const float* __restrict__ norm2,
                                                   const int* __restrict__ index,
                                                   float* __restrict__ cv,
                                                   int* __restrict__ ci) {
  __shared__ float vals[CHSZ];
  __shared__ float rv[4];
  __shared__ int   ri[4];
  int pb = blockIdx.x, ch = blockIdx.y;
  int p = pb / BS, b = pb - p*BS;
  int n0 = ch*CHSZ;
  int tid = threadIdx.x, lane = tid & 63, wv = tid >> 6;
  int idx = index[b];
  int bl = idx - HALFW; if (bl < 0) bl = 0;
  int bh = idx + HALFW; if (bh > NT-1) bh = NT-1;
  const float* n2 = norm2 + (size_t)p*NT;
  float cp = cpb[pb];
  for (int i = tid; i < CHSZ; i += 256) {
    int n = n0 + i;
    float d = dotp3[(size_t)pb*NT + n]
            + dotp3[(size_t)PB*NT + (size_t)pb*NT + n]
            + dotp3[2*(size_t)PB*NT + (size_t)pb*NT + n] + cp;
    float v = d / fmaxf(sqrtf(n2[n]), 1e-12f);
    if (n >= bl && n <= bh) v = -INFINITY;
    vals[i] = v;
  }
  __syncthreads();
  for (int it = 0; it < TOPM; it++) {
    float bv = -INFINITY; int bi = CHSZ;
    for (int i = tid; i < CHSZ; i += 256) {
      float v = vals[i];
      if (v > bv) { bv = v; bi = i; }
    }
    #pragma unroll
    for (int off=32; off>0; off>>=1) {
      float ov = __shfl_xor(bv, off);
      int   oi = __shfl_xor(bi, off);
      if (ov > bv || (ov == bv && oi < bi)) { bv = ov; bi = oi; }
    }
    if (lane == 0) { rv[wv] = bv; ri[wv] = bi; }
    __syncthreads();
    if (tid == 0) {
      float fv = rv[0]; int fi = ri[0];
      #pragma unroll
      for (int w2=1; w2<4; w2++)
        if (rv[w2] > fv || (rv[w2] == fv && ri[w2] < fi)) { fv = rv[w2]; fi = ri[w2]; }
      cv[(pb*NCH + ch)*TOPM + it] = fv;
      ci[(pb*NCH + ch)*TOPM + it] = n0 + fi;
      vals[fi] = -INFINITY;
    }
    __syncthreads();
  }
}

// ---------------- top-20 phase B: merge NCH x 20 candidates (exact; tie -> lower global index)
__global__ __launch_bounds__(64) void k_topk_merge(const float* __restrict__ cv,
                                                   const int* __restrict__ ci,
                                                   int* __restrict__ topm) {
  __shared__ float v[NCH*TOPM];
  __shared__ int   id[NCH*TOPM];
  int pb = blockIdx.x;
  int lane = threadIdx.x;
  for (int i = lane; i < NCH*TOPM; i += 64) {
    v[i]  = cv[pb*NCH*TOPM + i];
    id[i] = ci[pb*NCH*TOPM + i];
  }
  __syncthreads();
  for (int it = 0; it < TOPM; it++) {
    float bv = -INFINITY; int bi = 0x7fffffff;
    for (int i = lane; i < NCH*TOPM; i += 64) {
      float vv = v[i];
      int ii = id[i];
      if (vv > bv || (vv == bv && ii < bi)) { bv = vv; bi = ii; }
    }
    #pragma unroll
    for (int off=32; off>0; off>>=1) {
      float ov = __shfl_xor(bv, off);
      int   oi = __shfl_xor(bi, off);
      if (ov > bv || (ov == bv && oi < bi)) { bv = ov; bi = oi; }
    }
    if (lane == 0) topm[pb*TOPM + it] = bi;
    for (int i = lane; i < NCH*TOPM; i += 64)
      if (id[i] == bi) v[i] = -INFINITY;
    __syncthreads();
  }
}

// ---------------- v body: gathered y_mg rows
__device__ __forceinline__ void v_body(const float* __restrict__ ydata,
                                       const int* __restrict__ topm,
                                       float* __restrict__ vbuf,
                                       int bm, float* bpool) {
  float* row = bpool;          // 768
  float* m4  = bpool + 768;    // 192
  float* m2  = bpool + 960;    // 384
  int pb = bm / TOPM;
  int p = pb / BS;
  int n = topm[bm];
  int tid = threadIdx.x;
  const float* src = ydata + (size_t)n*PREDL*CH;
  for (int i=tid; i<PREDL*CH; i+=256) row[i]=src[i];
  __syncthreads();
  for (int i=tid; i<(PREDL/4)*CH; i+=256) {
    int j=i>>3, c=i&7;
    m4[i] = (row[(4*j)*CH+c]+row[(4*j+1)*CH+c]+row[(4*j+2)*CH+c]+row[(4*j+3)*CH+c])*0.25f;
  }
  for (int i=tid; i<(PREDL/2)*CH; i+=256) {
    int j=i>>3, c=i&7;
    m2[i] = (row[(2*j)*CH+c]+row[(2*j+1)*CH+c])*0.5f;
  }
  __syncthreads();
  float* dst = vbuf + (size_t)bm*PREDL*CH;
  for (int i=tid; i<PREDL*CH; i+=256) {
    int l=i>>3, c=i&7;
    float v;
    if (p==0)      v = m4[(l>>2)*CH+c] - m4[(PREDL/4-1)*CH+c];
    else if (p==1) v = m2[(l>>1)*CH+c] - m2[(PREDL/2-1)*CH+c];
    else           v = row[i] - row[(PREDL-1)*CH+c];
    dst[i] = v;
  }
}

// ---------------- scores body, group-collapsed per plane (hoisted kreg, R18-verified form)
template<int SH>
__device__ __forceinline__ void scores_body(
    const short* __restrict__ plane, int Kp,
    int pb, int sg,
    const int* __restrict__ topm,
    const float* __restrict__ xmg,
    const float* __restrict__ cst,
    float* __restrict__ nws,
    float* sc, int* tl, float* wred, float* lcst) {
  constexpr int UNQ = SEQL >> SH;      // 48 / 96 / 192
  constexpr int J   = TOPM * UNQ;      // 960 / 1920 / 3840
  constexpr int NU  = (J + 255) >> 8;  // 4 / 8 / 15
  constexpr bool FULL = (J % 256 == 0);
  int tid = threadIdx.x;
  int lane = tid & 63, wv = tid >> 6;
  if (tid < TOPM) tl[tid] = topm[pb*TOPM + tid];
  if (tid >= 32 && tid < 32+81) lcst[tid-32] = cst[tid-32];
  __syncthreads();
  uint4 kreg[NU];
  #pragma unroll
  for (int u=0; u<NU; u++) {
    int j = tid + u*256;
    if (FULL || j < J) {
      int m = j / UNQ, jj = j - m*UNQ;
      kreg[u] = *reinterpret_cast<const uint4*>(plane + (size_t)tl[m]*Kp + jj*8);
    }
  }
  for (int s8 = 0; s8 < 8; s8++) {
    int s = sg*8 + s8;
    int qr = pb*SEQL + s;
    float4 qa = *reinterpret_cast<const float4*>(&xmg[(size_t)qr*8]);
    float4 qc = *reinterpret_cast<const float4*>(&xmg[(size_t)qr*8+4]);
    float xq[8] = {qa.x,qa.y,qa.z,qa.w,qc.x,qc.y,qc.z,qc.w};
    float q[8];
    #pragma unroll
    for (int e=0;e<8;e++) {
      float ss = lcst[72+e];
      #pragma unroll
      for (int c=0;c<8;c++) ss += xq[c]*lcst[c*8+e];
      q[e] = ss;
    }
    float qb_s = lcst[80];
    #pragma unroll
    for (int c=0;c<8;c++) qb_s += xq[c]*lcst[64+c];
    float ms[NU];
    float lmax = -INFINITY;
    #pragma unroll
    for (int u=0; u<NU; u++) {
      int j = tid + u*256;
      if (FULL || j < J) {
        uint4 w = kreg[u];
        float s0 = qb_s;
        s0 += q[0]*bflo(w.x) + q[1]*bfhi(w.x);
        s0 += q[2]*bflo(w.y) + q[3]*bfhi(w.y);
        s0 += q[4]*bflo(w.z) + q[5]*bfhi(w.z);
        s0 += q[6]*bflo(w.w) + q[7]*bfhi(w.w);
        s0 *= RSQRT_DM;
        ms[u] = s0;
        lmax = fmaxf(lmax, s0);
      } else ms[u] = -INFINITY;
    }
    #pragma unroll
    for (int off=32; off>0; off>>=1) lmax = fmaxf(lmax, __shfl_xor(lmax, off));
    if (lane==0) wred[wv] = lmax;
    __syncthreads();
    float mx = fmaxf(fmaxf(wred[0],wred[1]),fmaxf(wred[2],wred[3]));
    float lsum = 0.f;
    #pragma unroll
    for (int u=0; u<NU; u++) {
      int j = tid + u*256;
      if (FULL || j < J) {
        float e = __expf(ms[u]-mx);
        sc[j] = e;
        lsum += e;
      }
    }
    #pragma unroll
    for (int off=32; off>0; off>>=1) lsum += __shfl_xor(lsum, off);
    if (lane==0) wred[4+wv] = lsum;
    __syncthreads();
    float invZ = 1.f / (wred[4]+wred[5]+wred[6]+wred[7]);
    for (int m = wv; m < TOPM; m += 4) {
      float v = 0.f;
      #pragma unroll
      for (int jj = 0; jj < UNQ; jj += 64) {
        int j2 = jj + lane;
        if (UNQ % 64 == 0 || j2 < UNQ) v += sc[m*UNQ + j2];
      }
      #pragma unroll
      for (int off=32; off>0; off>>=1) v += __shfl_xor(v, off);
      if (lane==0) nws[((size_t)pb*SEQL + s)*TOPM + m] = v * invZ;
    }
    __syncthreads();
  }
}

// ---------------- fused back: scores | v-gather
__global__ __launch_bounds__(256) void k_back(const __hip_bfloat16* __restrict__ m0,
                                              const __hip_bfloat16* __restrict__ m1,
                                              const __hip_bfloat16* __restrict__ m2,
                                              const int* __restrict__ topm,
                                              const float* __restrict__ xmg,
                                              const float* __restrict__ cst,
                                              float* __restrict__ nws,
                                              const float* __restrict__ ydata,
                                              float* __restrict__ vbuf) {
  __shared__ float bpool[3968];
  int bid = blockIdx.x;
  if (bid < PB*24) {
    int pb = bid / 24, sg = bid - (bid/24)*24;
    int p = pb / BS;
    float* sc = bpool;
    int* tl = (int*)(bpool + 3840);
    float* wred = bpool + 3864;
    float* lcst = bpool + 3872;
    if (p == 0)
      scores_body<2>((const short*)m0, K0R, pb, sg, topm, xmg, cst, nws, sc, tl, wred, lcst);
    else if (p == 1)
      scores_body<1>((const short*)m1, K1R, pb, sg, topm, xmg, cst, nws, sc, tl, wred, lcst);
    else
      scores_body<0>((const short*)m2, K2R, pb, sg, topm, xmg, cst, nws, sc, tl, wred, lcst);
  } else {
    v_body(ydata, topm, vbuf, bid - PB*24, bpool);
  }
}

// ---------------- nw softmax over m, then out = sum_m nw[m] * v[m]
__global__ __launch_bounds__(256) void k_out(const float* __restrict__ nws,
                                             const float* __restrict__ vbuf,
                                             float* __restrict__ out) {
  __shared__ float nwp[TOPM];
  __shared__ float nwf[TOPM];
  int pb = blockIdx.x;
  int tid = threadIdx.x;
  if (tid < TOPM) {
    float s=0.f;
    for (int ss=0; ss<SEQL; ss++) s += nws[((size_t)pb*SEQL+ss)*TOPM + tid];
    nwp[tid] = s;
  }
  __syncthreads();
  if (tid==0) {
    float mx=-INFINITY;
    for (int m=0;m<TOPM;m++) mx=fmaxf(mx,nwp[m]);
    float Z=0.f;
    for (int m=0;m<TOPM;m++){ float e=expf(nwp[m]-mx); nwf[m]=e; Z+=e; }
    float iz=1.f/Z;
    for (int m=0;m<TOPM;m++) nwf[m]*=iz;
  }
  __syncthreads();
  for (int i=tid; i<PREDL*CH; i+=256) {
    float o=0.f;
    #pragma unroll
    for (int m=0;m<TOPM;m++) o += nwf[m]*vbuf[((size_t)pb*TOPM+m)*PREDL*CH + i];
    out[(size_t)pb*PREDL*CH + i] = o;
  }
}

extern "C" void kernel_launch(void* const* d_in, const int* in_sizes, int n_in,
                              void* d_out, int out_size, void* d_ws, size_t ws_size,
                              hipStream_t stream) {
  const float* x     = (const float*)d_in[0];
  const int*   index = (const int*)  d_in[1];
  const float* train = (const float*)d_in[2];
  const float* ydata = (const float*)d_in[3];
  const float* Wsim  = (const float*)d_in[4];
  const float* bsim  = (const float*)d_in[5];
  const float* Wq    = (const float*)d_in[6];
  const float* bq    = (const float*)d_in[7];
  const float* Wk    = (const float*)d_in[8];
  const float* bk    = (const float*)d_in[9];
  float* out = (float*)d_out;

  float* ws = (float*)d_ws;
  size_t off = 0;
  auto alloc = [&](size_t n)->float* { float* pp = ws + off; off += (n + 63) & ~(size_t)63; return pp; };
  __hip_bfloat16* m0b = (__hip_bfloat16*)alloc((size_t)NRP3*K0R/2);
  __hip_bfloat16* m1b = (__hip_bfloat16*)alloc((size_t)NRP3*K1R/2);
  __hip_bfloat16* m2b = (__hip_bfloat16*)alloc((size_t)NRP3*K2R/2);
  __hip_bfloat16* wt0 = (__hip_bfloat16*)alloc((size_t)FD*K0R/2);
  __hip_bfloat16* wt1 = (__hip_bfloat16*)alloc((size_t)FD*K1R/2);
  __hip_bfloat16* wt2 = (__hip_bfloat16*)alloc((size_t)FD*K2R/2);
  __hip_bfloat16* trH = (__hip_bfloat16*)alloc((size_t)(NRB2*128)*FD/2);
  __hip_bfloat16* trL = (__hip_bfloat16*)alloc((size_t)(NRB2*128)*FD/2);
  __hip_bfloat16* tadjH = (__hip_bfloat16*)alloc((size_t)128*FD/2);
  __hip_bfloat16* tadjL = (__hip_bfloat16*)alloc((size_t)128*FD/2);
  float* x_mg     = alloc((size_t)NPER*BS*FD);
  float* bx       = alloc((size_t)PB*FD);             // becomes u after k_bxnorm
  float* cpb      = alloc(PB);
  float* gpart    = alloc((size_t)KS*PB*FD);          // reused: bx partials, then t partials
  float* part     = alloc((size_t)NPER*NRP3*PCOLS);
  float* norm2    = alloc(NROWS);
  float* dotp3    = alloc((size_t)3*PB*NT);           // 11.5 MB: hh / hl / lh term planes
  float* cv       = alloc((size_t)PB*NCH*TOPM);
  int*   ci       = (int*)alloc(PB*NCH*TOPM);
  int*   topm     = (int*)alloc(PB*TOPM);
  float* cst      = alloc(128);
  float* vbuf     = alloc((size_t)PB*TOPM*PREDL*CH);
  float* nws      = alloc((size_t)PB*SEQL*TOPM);
  if (off * sizeof(float) > ws_size) return;          // insufficient scratch -> visible failure

  k_front<<<NT + NWTG + BS, 256, 0, stream>>>(x, train, x_mg, m0b, m1b, m2b, trH, trL,
                                              Wsim, wt0, wt1, wt2, Wq, bq, Wk, bk, cst);
  k_bx_part<<<dim3(24, KS), 256, 0, stream>>>(x_mg, Wsim, gpart);
  k_bxnorm<<<PB, 256, 0, stream>>>(gpart, bsim, bx, cpb);
  k_t_part<<<dim3(24, KS), 256, 0, stream>>>(bx, Wsim, gpart);
  k_tred_adj<<<PB, 192, 0, stream>>>(gpart, tadjH, tadjL);
  k_gemms<<<3*NWG3 + NB_DOT, 512, 0, stream>>>(m0b, m1b, m2b, wt0, wt1, wt2, bsim, part,
                                               tadjH, tadjL, trH, trL, dotp3);
  k_norm_red<<<(NROWS+255)/256, 256, 0, stream>>>(part, norm2);
  k_topk_part<<<dim3(PB, NCH), 256, 0, stream>>>(dotp3, cpb, norm2, index, cv, ci);
  k_topk_merge<<<PB, 64, 0, stream>>>(cv, ci, topm);
  k_back<<<PB*24 + PB*TOPM, 256, 0, stream>>>(m0b, m1b, m2b, topm, x_mg, cst, nws,
                                              ydata, vbuf);
  k_out<<<PB, 256, 0, stream>>>(nws, vbuf, out);
}